// Round 1
// baseline (654.842 us; speedup 1.0000x reference)
//
#include <hip/hip_runtime.h>
#include <hip/hip_bf16.h>
#include <stdint.h>

#define BATCH 2
#define SEQLEN 2048
#define DMODEL 1024
#define DINNER 2048
#define DSTATE 16
#define DTRANK 64
#define NPROJ 128            // 96 padded to 128 for the MFMA GEMM
#define NROWS (BATCH*SEQLEN) // 4096

typedef __bf16 bf16;
typedef __bf16 bf16x8 __attribute__((ext_vector_type(8)));
typedef __bf16 bf16x4 __attribute__((ext_vector_type(4)));
typedef float  floatx4 __attribute__((ext_vector_type(4)));

__device__ __forceinline__ float sigmoidf_(float x) { return 1.f / (1.f + __expf(-x)); }
__device__ __forceinline__ float siluf_(float x)    { return x * sigmoidf_(x); }

__device__ __forceinline__ void gload_lds16(const void* gsrc, void* ldsdst) {
  auto g = (const __attribute__((address_space(1))) uint32_t*)(uintptr_t)gsrc;
  uint32_t lo = (uint32_t)(uintptr_t)ldsdst;
  auto l = (__attribute__((address_space(3))) uint32_t*)lo;
  __builtin_amdgcn_global_load_lds(g, l, 16, 0, 0);
}

// ---------------- casts ----------------
__global__ __launch_bounds__(256) void cast_bf16_k(const float* __restrict__ in,
                                                   bf16* __restrict__ out, int n4) {
  int i = blockIdx.x * 256 + threadIdx.x;
  if (i < n4) {
    floatx4 v = *(const floatx4*)&in[(size_t)i * 4];
    bf16x4 o;
    #pragma unroll
    for (int j = 0; j < 4; ++j) o[j] = (bf16)v[j];
    *(bf16x4*)&out[(size_t)i * 4] = o;
  }
}

// x_proj_w (96x2048) -> bf16 (128x2048), rows 96..127 zero
__global__ __launch_bounds__(256) void cast_pad_xw_k(const float* __restrict__ in,
                                                     bf16* __restrict__ out) {
  int i = blockIdx.x * 256 + threadIdx.x;   // 65536 threads, 4 elems each
  int idx = i * 4;
  int row = idx >> 11;
  bf16x4 o;
  if (row < 96) {
    floatx4 v = *(const floatx4*)&in[idx];
    #pragma unroll
    for (int j = 0; j < 4; ++j) o[j] = (bf16)v[j];
  } else {
    #pragma unroll
    for (int j = 0; j < 4; ++j) o[j] = (bf16)0.f;
  }
  *(bf16x4*)&out[idx] = o;
}

// ---------------- bf16 NT GEMM (m97 structure): C[M,N] = A[M,K] * B[N,K]^T ----------------
template <typename OT>
__global__ __launch_bounds__(256) void gemm_bt(const bf16* __restrict__ A,
                                               const bf16* __restrict__ Bm,
                                               OT* __restrict__ C,
                                               int M, int N, int K) {
  __shared__ bf16 As[128 * 32];
  __shared__ bf16 Bs[128 * 32];
  const int tid  = threadIdx.x;
  const int lane = tid & 63;
  const int wave = tid >> 6;
  const int bm = blockIdx.y * 128;
  const int bn = blockIdx.x * 128;
  const int wr = (wave >> 1) << 6;
  const int wc = (wave & 1) << 6;
  const int fr = lane & 15;
  const int fq = lane >> 4;

  const int srow  = tid >> 2;         // 0..63
  const int skoff = (tid & 3) << 3;   // 0,8,16,24 (bf16 elems)
  const bf16* ga0 = A  + (size_t)(bm + srow) * K + skoff;
  const bf16* ga1 = A  + (size_t)(bm + 64 + srow) * K + skoff;
  const bf16* gb0 = Bm + (size_t)(bn + srow) * K + skoff;
  const bf16* gb1 = Bm + (size_t)(bn + 64 + srow) * K + skoff;
  char* la0 = (char*)As + (wave << 10);
  char* la1 = (char*)As + 4096 + (wave << 10);
  char* lb0 = (char*)Bs + (wave << 10);
  char* lb1 = (char*)Bs + 4096 + (wave << 10);

  floatx4 acc[4][4];
  #pragma unroll
  for (int i = 0; i < 4; ++i)
    #pragma unroll
    for (int j = 0; j < 4; ++j)
      #pragma unroll
      for (int r = 0; r < 4; ++r) acc[i][j][r] = 0.f;

  for (int k0 = 0; k0 < K; k0 += 32) {
    gload_lds16(ga0 + k0, la0);
    gload_lds16(ga1 + k0, la1);
    gload_lds16(gb0 + k0, lb0);
    gload_lds16(gb1 + k0, lb1);
    __syncthreads();
    bf16x8 af[4], bfr[4];
    #pragma unroll
    for (int i = 0; i < 4; ++i)
      af[i] = *(const bf16x8*)&As[(wr + (i << 4) + fr) * 32 + (fq << 3)];
    #pragma unroll
    for (int j = 0; j < 4; ++j)
      bfr[j] = *(const bf16x8*)&Bs[(wc + (j << 4) + fr) * 32 + (fq << 3)];
    #pragma unroll
    for (int i = 0; i < 4; ++i)
      #pragma unroll
      for (int j = 0; j < 4; ++j)
        acc[i][j] = __builtin_amdgcn_mfma_f32_16x16x32_bf16(af[i], bfr[j], acc[i][j], 0, 0, 0);
    __syncthreads();
  }
  #pragma unroll
  for (int i = 0; i < 4; ++i) {
    const int row = bm + wr + (i << 4) + (fq << 2);
    #pragma unroll
    for (int j = 0; j < 4; ++j) {
      const int col = bn + wc + (j << 4) + fr;
      #pragma unroll
      for (int r = 0; r < 4; ++r)
        C[(size_t)(row + r) * N + col] = (OT)acc[i][j][r];
    }
  }
}

// ---------------- depthwise causal conv(4) + bias + SiLU ----------------
// reads xs = xr[:, 0:2048] (bf16), writes u_btd (bf16, (b,t,d)) and u_dtl (f32, (b,d,t))
__global__ __launch_bounds__(256) void conv_silu_k(const bf16* __restrict__ xr,
                                                   const float* __restrict__ cw,
                                                   const float* __restrict__ cb,
                                                   bf16* __restrict__ u_btd,
                                                   float* __restrict__ u_dtl) {
  __shared__ float tile[32][65];
  const int tid = threadIdx.x;
  const int d0 = blockIdx.x << 6;   // 64 channels per block
  const int t0 = blockIdx.y << 5;   // 32 timesteps per block
  const int b  = blockIdx.z;
  const int dl = tid & 63, tq = tid >> 6;
  const int d  = d0 + dl;
  const float w0 = cw[d * 4 + 0], w1 = cw[d * 4 + 1], w2 = cw[d * 4 + 2], w3 = cw[d * 4 + 3];
  const float bias = cb[d];
  #pragma unroll
  for (int i = 0; i < 8; ++i) {
    const int t = tq * 8 + i;       // 0..31
    const int tg = t0 + t;
    float acc = bias;
    {
      int tt = tg - 3;
      if (tt >= 0) acc += w0 * (float)xr[((size_t)b * SEQLEN + tt) * 4096 + d];
    }
    {
      int tt = tg - 2;
      if (tt >= 0) acc += w1 * (float)xr[((size_t)b * SEQLEN + tt) * 4096 + d];
    }
    {
      int tt = tg - 1;
      if (tt >= 0) acc += w2 * (float)xr[((size_t)b * SEQLEN + tt) * 4096 + d];
    }
    acc += w3 * (float)xr[((size_t)b * SEQLEN + tg) * 4096 + d];
    const float uval = siluf_(acc);
    u_btd[((size_t)b * SEQLEN + tg) * DINNER + d] = (bf16)uval;
    tile[t][dl] = uval;
  }
  __syncthreads();
  const int dr = tid >> 2;            // 0..63
  const int tcol = (tid & 3) << 3;    // 0,8,16,24
  float vals[8];
  #pragma unroll
  for (int i = 0; i < 8; ++i) vals[i] = tile[tcol + i][dr];
  #pragma unroll
  for (int i = 0; i < 8; ++i)
    u_dtl[((size_t)b * DINNER + d0 + dr) * SEQLEN + t0 + tcol + i] = vals[i];
}

// ---------------- dt projection + softplus + clamp, transposed output (b,d,t) ----------------
__global__ __launch_bounds__(256) void dtproj_k(const float* __restrict__ x_dbl,
                                                const float* __restrict__ w,
                                                const float* __restrict__ bias,
                                                float* __restrict__ dt_t) {
  __shared__ float r_s[64][65];
  __shared__ float w_s[64][65];
  const int tid  = threadIdx.x;
  const int d0   = blockIdx.x << 6;
  const int row0 = blockIdx.y << 6;
  #pragma unroll
  for (int j = 0; j < 4; ++j) {
    int id = tid + (j << 8);          // 0..1023
    int r  = id >> 4;
    int kq = (id & 15) << 2;
    floatx4 v = *(const floatx4*)&x_dbl[(size_t)(row0 + r) * NPROJ + kq];
    r_s[r][kq] = v[0]; r_s[r][kq + 1] = v[1]; r_s[r][kq + 2] = v[2]; r_s[r][kq + 3] = v[3];
    floatx4 ww = *(const floatx4*)&w[(size_t)(d0 + r) * 64 + kq];
    w_s[r][kq] = ww[0]; w_s[r][kq + 1] = ww[1]; w_s[r][kq + 2] = ww[2]; w_s[r][kq + 3] = ww[3];
  }
  __syncthreads();
  const int tl = tid & 15, dl = tid >> 4;
  float acc[4][4] = {};               // [t][d]
  #pragma unroll 8
  for (int k = 0; k < 64; ++k) {
    float a[4], bb[4];
    #pragma unroll
    for (int i = 0; i < 4; ++i) a[i] = r_s[tl * 4 + i][k];
    #pragma unroll
    for (int j = 0; j < 4; ++j) bb[j] = w_s[dl + (j << 4)][k];
    #pragma unroll
    for (int i = 0; i < 4; ++i)
      #pragma unroll
      for (int j = 0; j < 4; ++j) acc[i][j] += a[i] * bb[j];
  }
  const int bb_ = row0 >> 11;
  const int tbase = (row0 & 2047) + tl * 4;
  #pragma unroll
  for (int j = 0; j < 4; ++j) {
    const int dd = d0 + dl + (j << 4);
    const float bsv = bias[dd];
    floatx4 o;
    #pragma unroll
    for (int i = 0; i < 4; ++i) {
      float v = acc[i][j] + bsv;
      float sp = (v > 20.f) ? v : __logf(1.f + __expf(v));
      o[i] = fminf(sp, 10.f);
    }
    *(floatx4*)&dt_t[((size_t)bb_ * DINNER + dd) * SEQLEN + tbase] = o;
  }
}

// ---------------- selective scan ----------------
#define TCH 128
__global__ __launch_bounds__(256) void scan_k(const float* __restrict__ dt_t,
                                              const float* __restrict__ u_dtl,
                                              const float* __restrict__ x_dbl,
                                              const float* __restrict__ A_log,
                                              const float* __restrict__ Dp,
                                              float* __restrict__ y) {
  __shared__ float dtc[16][132];
  __shared__ float uc[16][132];
  __shared__ float Bc[TCH][20];
  __shared__ float Cc[TCH][20];
  __shared__ float ytile[TCH][17];
  const int tid = threadIdx.x;
  const int b   = blockIdx.y;
  const int d0  = blockIdx.x << 4;
  const int s   = tid & 15, ch = tid >> 4;
  const int d   = d0 + ch;
  const float Av = -__expf(A_log[d * DSTATE + s]);
  const float Dv = Dp[d];
  float h = 0.f;
  for (int t0 = 0; t0 < SEQLEN; t0 += TCH) {
    #pragma unroll
    for (int j = 0; j < 2; ++j) {
      int lin = tid + (j << 8);       // 0..511
      int c2  = lin >> 5;             // 0..15
      int tq  = (lin & 31) << 2;      // 0..124
      floatx4 v = *(const floatx4*)&dt_t[((size_t)b * DINNER + d0 + c2) * SEQLEN + t0 + tq];
      *(floatx4*)&dtc[c2][tq] = v;
      floatx4 w = *(const floatx4*)&u_dtl[((size_t)b * DINNER + d0 + c2) * SEQLEN + t0 + tq];
      *(floatx4*)&uc[c2][tq] = w;
    }
    #pragma unroll
    for (int j = 0; j < 2; ++j) {
      int lin = tid + (j << 8);
      int t  = lin >> 2;              // 0..127
      int sq = (lin & 3) << 2;        // 0..12
      floatx4 v = *(const floatx4*)&x_dbl[((size_t)b * SEQLEN + t0 + t) * NPROJ + 64 + sq];
      *(floatx4*)&Bc[t][sq] = v;
      floatx4 w = *(const floatx4*)&x_dbl[((size_t)b * SEQLEN + t0 + t) * NPROJ + 80 + sq];
      *(floatx4*)&Cc[t][sq] = w;
    }
    __syncthreads();
    #pragma unroll 4
    for (int t = 0; t < TCH; ++t) {
      const float dtv = dtc[ch][t];
      const float uv  = uc[ch][t];
      const float dA  = __expf(dtv * Av);
      h = dA * h + (dtv * uv) * Bc[t][s];
      float yp = h * Cc[t][s];
      yp += __shfl_xor(yp, 1, 16);
      yp += __shfl_xor(yp, 2, 16);
      yp += __shfl_xor(yp, 4, 16);
      yp += __shfl_xor(yp, 8, 16);
      if (s == 0) ytile[t][ch] = yp + Dv * uv;
    }
    __syncthreads();
    #pragma unroll
    for (int j = 0; j < 8; ++j) {
      int lin = tid + (j << 8);
      int t = lin >> 4, dl2 = lin & 15;
      y[((size_t)b * SEQLEN + t0 + t) * DINNER + d0 + dl2] = ytile[t][dl2];
    }
    __syncthreads();
  }
}

// ---------------- gate: yres = bf16(y * silu(res)) ----------------
__global__ __launch_bounds__(256) void ymul_k(const float* __restrict__ y,
                                              const bf16* __restrict__ xr,
                                              bf16* __restrict__ yres) {
  const int idx = (blockIdx.x * 256 + threadIdx.x) * 4;
  const int row = idx >> 11;
  const int dcol = idx & 2047;
  floatx4 yv = *(const floatx4*)&y[idx];
  bf16x4 rv = *(const bf16x4*)&xr[(size_t)row * 4096 + 2048 + dcol];
  bf16x4 o;
  #pragma unroll
  for (int i = 0; i < 4; ++i) {
    float r = (float)rv[i];
    o[i] = (bf16)(yv[i] * siluf_(r));
  }
  *(bf16x4*)&yres[idx] = o;
}

extern "C" void kernel_launch(void* const* d_in, const int* in_sizes, int n_in,
                              void* d_out, int out_size, void* d_ws, size_t ws_size,
                              hipStream_t stream) {
  const float* x         = (const float*)d_in[0];
  const float* in_proj_w = (const float*)d_in[1];
  const float* conv_w    = (const float*)d_in[2];
  const float* conv_b    = (const float*)d_in[3];
  const float* x_proj_w  = (const float*)d_in[4];
  const float* dt_proj_w = (const float*)d_in[5];
  const float* dt_proj_b = (const float*)d_in[6];
  const float* A_log     = (const float*)d_in[7];
  const float* Dp        = (const float*)d_in[8];
  const float* out_proj_w= (const float*)d_in[9];
  float* out = (float*)d_out;

  char* ws = (char*)d_ws;
  size_t off = 0;
  auto alloc = [&](size_t bytes) -> void* {
    void* p = ws + off;
    off += (bytes + 255) & ~(size_t)255;
    return p;
  };
  bf16*  x_bf   = (bf16*) alloc((size_t)NROWS * DMODEL * 2);
  bf16*  wi_bf  = (bf16*) alloc((size_t)2 * DINNER * DMODEL * 2);
  bf16*  wo_bf  = (bf16*) alloc((size_t)DMODEL * DINNER * 2);
  bf16*  xw_bf  = (bf16*) alloc((size_t)NPROJ * DINNER * 2);
  bf16*  xr     = (bf16*) alloc((size_t)NROWS * 4096 * 2);
  bf16*  u_btd  = (bf16*) alloc((size_t)NROWS * DINNER * 2);
  float* u_dtl  = (float*)alloc((size_t)BATCH * DINNER * SEQLEN * 4);
  float* x_dbl  = (float*)alloc((size_t)NROWS * NPROJ * 4);
  float* dt_t   = (float*)alloc((size_t)BATCH * DINNER * SEQLEN * 4);
  float* yb     = (float*)alloc((size_t)NROWS * DINNER * 4);
  bf16*  yres   = (bf16*) alloc((size_t)NROWS * DINNER * 2);

  cast_bf16_k<<<(NROWS * DMODEL / 4 + 255) / 256, 256, 0, stream>>>(x, x_bf, NROWS * DMODEL / 4);
  cast_bf16_k<<<(2 * DINNER * DMODEL / 4 + 255) / 256, 256, 0, stream>>>(in_proj_w, wi_bf, 2 * DINNER * DMODEL / 4);
  cast_bf16_k<<<(DMODEL * DINNER / 4 + 255) / 256, 256, 0, stream>>>(out_proj_w, wo_bf, DMODEL * DINNER / 4);
  cast_pad_xw_k<<<NPROJ * DINNER / 4 / 256, 256, 0, stream>>>(x_proj_w, xw_bf);

  // in_proj: (4096 x 4096) = x_bf (4096x1024) @ wi_bf^T
  gemm_bt<bf16><<<dim3(32, 32), 256, 0, stream>>>(x_bf, wi_bf, xr, NROWS, 4096, DMODEL);
  // conv + SiLU
  conv_silu_k<<<dim3(DINNER / 64, SEQLEN / 32, BATCH), 256, 0, stream>>>(xr, conv_w, conv_b, u_btd, u_dtl);
  // x_proj: (4096 x 128) = u (4096x2048) @ xw^T
  gemm_bt<float><<<dim3(1, 32), 256, 0, stream>>>(u_btd, xw_bf, x_dbl, NROWS, NPROJ, DINNER);
  // dt proj + softplus + clamp -> (b,d,t)
  dtproj_k<<<dim3(DINNER / 64, NROWS / 64), 256, 0, stream>>>(x_dbl, dt_proj_w, dt_proj_b, dt_t);
  // selective scan
  scan_k<<<dim3(DINNER / 16, BATCH), 256, 0, stream>>>(dt_t, u_dtl, x_dbl, A_log, Dp, yb);
  // gate
  ymul_k<<<NROWS * DINNER / 4 / 256, 256, 0, stream>>>(yb, xr, yres);
  // out_proj: (4096 x 1024) = yres (4096x2048) @ wo^T
  gemm_bt<float><<<dim3(DMODEL / 128, NROWS / 128), 256, 0, stream>>>(yres, wo_bf, out, NROWS, DMODEL, DINNER);
}

// Round 2
// 392.074 us; speedup vs baseline: 1.6702x; 1.6702x over previous
//
#include <hip/hip_runtime.h>
#include <hip/hip_bf16.h>
#include <stdint.h>

#define BATCH 2
#define SEQLEN 2048
#define DMODEL 1024
#define DINNER 2048
#define DSTATE 16
#define DTRANK 64
#define NPROJ 128            // 96 padded to 128 for the MFMA GEMM
#define NROWS (BATCH*SEQLEN) // 4096
#define NCHUNK 32
#define TCC 64               // timesteps per scan chunk

typedef __bf16 bf16;
typedef __bf16 bf16x8 __attribute__((ext_vector_type(8)));
typedef __bf16 bf16x4 __attribute__((ext_vector_type(4)));
typedef float  floatx4 __attribute__((ext_vector_type(4)));

__device__ __forceinline__ float sigmoidf_(float x) { return 1.f / (1.f + __expf(-x)); }
__device__ __forceinline__ float siluf_(float x)    { return x * sigmoidf_(x); }

__device__ __forceinline__ void gload_lds16(const void* gsrc, void* ldsdst) {
  auto g = (const __attribute__((address_space(1))) uint32_t*)(uintptr_t)gsrc;
  uint32_t lo = (uint32_t)(uintptr_t)ldsdst;
  auto l = (__attribute__((address_space(3))) uint32_t*)lo;
  __builtin_amdgcn_global_load_lds(g, l, 16, 0, 0);
}

// ---------------- casts ----------------
__global__ __launch_bounds__(256) void cast_bf16_k(const float* __restrict__ in,
                                                   bf16* __restrict__ out, int n4) {
  int i = blockIdx.x * 256 + threadIdx.x;
  if (i < n4) {
    floatx4 v = *(const floatx4*)&in[(size_t)i * 4];
    bf16x4 o;
    #pragma unroll
    for (int j = 0; j < 4; ++j) o[j] = (bf16)v[j];
    *(bf16x4*)&out[(size_t)i * 4] = o;
  }
}

// x_proj_w (96x2048) -> bf16 (128x2048), rows 96..127 zero
__global__ __launch_bounds__(256) void cast_pad_xw_k(const float* __restrict__ in,
                                                     bf16* __restrict__ out) {
  int i = blockIdx.x * 256 + threadIdx.x;   // 65536 threads, 4 elems each
  int idx = i * 4;
  int row = idx >> 11;
  bf16x4 o;
  if (row < 96) {
    floatx4 v = *(const floatx4*)&in[idx];
    #pragma unroll
    for (int j = 0; j < 4; ++j) o[j] = (bf16)v[j];
  } else {
    #pragma unroll
    for (int j = 0; j < 4; ++j) o[j] = (bf16)0.f;
  }
  *(bf16x4*)&out[idx] = o;
}

// ---------------- bf16 NT GEMM (m97 structure): C[M,N] = A[M,K] * B[N,K]^T ----------------
template <typename OT>
__global__ __launch_bounds__(256) void gemm_bt(const bf16* __restrict__ A,
                                               const bf16* __restrict__ Bm,
                                               OT* __restrict__ C,
                                               int M, int N, int K) {
  __shared__ bf16 As[128 * 32];
  __shared__ bf16 Bs[128 * 32];
  const int tid  = threadIdx.x;
  const int lane = tid & 63;
  const int wave = tid >> 6;
  const int bm = blockIdx.y * 128;
  const int bn = blockIdx.x * 128;
  const int wr = (wave >> 1) << 6;
  const int wc = (wave & 1) << 6;
  const int fr = lane & 15;
  const int fq = lane >> 4;

  const int srow  = tid >> 2;         // 0..63
  const int skoff = (tid & 3) << 3;   // 0,8,16,24 (bf16 elems)
  const bf16* ga0 = A  + (size_t)(bm + srow) * K + skoff;
  const bf16* ga1 = A  + (size_t)(bm + 64 + srow) * K + skoff;
  const bf16* gb0 = Bm + (size_t)(bn + srow) * K + skoff;
  const bf16* gb1 = Bm + (size_t)(bn + 64 + srow) * K + skoff;
  char* la0 = (char*)As + (wave << 10);
  char* la1 = (char*)As + 4096 + (wave << 10);
  char* lb0 = (char*)Bs + (wave << 10);
  char* lb1 = (char*)Bs + 4096 + (wave << 10);

  floatx4 acc[4][4];
  #pragma unroll
  for (int i = 0; i < 4; ++i)
    #pragma unroll
    for (int j = 0; j < 4; ++j)
      #pragma unroll
      for (int r = 0; r < 4; ++r) acc[i][j][r] = 0.f;

  for (int k0 = 0; k0 < K; k0 += 32) {
    gload_lds16(ga0 + k0, la0);
    gload_lds16(ga1 + k0, la1);
    gload_lds16(gb0 + k0, lb0);
    gload_lds16(gb1 + k0, lb1);
    __syncthreads();
    bf16x8 af[4], bfr[4];
    #pragma unroll
    for (int i = 0; i < 4; ++i)
      af[i] = *(const bf16x8*)&As[(wr + (i << 4) + fr) * 32 + (fq << 3)];
    #pragma unroll
    for (int j = 0; j < 4; ++j)
      bfr[j] = *(const bf16x8*)&Bs[(wc + (j << 4) + fr) * 32 + (fq << 3)];
    #pragma unroll
    for (int i = 0; i < 4; ++i)
      #pragma unroll
      for (int j = 0; j < 4; ++j)
        acc[i][j] = __builtin_amdgcn_mfma_f32_16x16x32_bf16(af[i], bfr[j], acc[i][j], 0, 0, 0);
    __syncthreads();
  }
  #pragma unroll
  for (int i = 0; i < 4; ++i) {
    const int row = bm + wr + (i << 4) + (fq << 2);
    #pragma unroll
    for (int j = 0; j < 4; ++j) {
      const int col = bn + wc + (j << 4) + fr;
      #pragma unroll
      for (int r = 0; r < 4; ++r)
        C[(size_t)(row + r) * N + col] = (OT)acc[i][j][r];
    }
  }
}

// ---------------- depthwise causal conv(4) + bias + SiLU ----------------
__global__ __launch_bounds__(256) void conv_silu_k(const bf16* __restrict__ xr,
                                                   const float* __restrict__ cw,
                                                   const float* __restrict__ cb,
                                                   bf16* __restrict__ u_btd,
                                                   float* __restrict__ u_dtl) {
  __shared__ float tile[32][65];
  const int tid = threadIdx.x;
  const int d0 = blockIdx.x << 6;   // 64 channels per block
  const int t0 = blockIdx.y << 5;   // 32 timesteps per block
  const int b  = blockIdx.z;
  const int dl = tid & 63, tq = tid >> 6;
  const int d  = d0 + dl;
  const float w0 = cw[d * 4 + 0], w1 = cw[d * 4 + 1], w2 = cw[d * 4 + 2], w3 = cw[d * 4 + 3];
  const float bias = cb[d];
  #pragma unroll
  for (int i = 0; i < 8; ++i) {
    const int t = tq * 8 + i;       // 0..31
    const int tg = t0 + t;
    float acc = bias;
    {
      int tt = tg - 3;
      if (tt >= 0) acc += w0 * (float)xr[((size_t)b * SEQLEN + tt) * 4096 + d];
    }
    {
      int tt = tg - 2;
      if (tt >= 0) acc += w1 * (float)xr[((size_t)b * SEQLEN + tt) * 4096 + d];
    }
    {
      int tt = tg - 1;
      if (tt >= 0) acc += w2 * (float)xr[((size_t)b * SEQLEN + tt) * 4096 + d];
    }
    acc += w3 * (float)xr[((size_t)b * SEQLEN + tg) * 4096 + d];
    const float uval = siluf_(acc);
    u_btd[((size_t)b * SEQLEN + tg) * DINNER + d] = (bf16)uval;
    tile[t][dl] = uval;
  }
  __syncthreads();
  const int dr = tid >> 2;            // 0..63
  const int tcol = (tid & 3) << 3;    // 0,8,16,24
  float vals[8];
  #pragma unroll
  for (int i = 0; i < 8; ++i) vals[i] = tile[tcol + i][dr];
  #pragma unroll
  for (int i = 0; i < 8; ++i)
    u_dtl[((size_t)b * DINNER + d0 + dr) * SEQLEN + t0 + tcol + i] = vals[i];
}

// ---------------- dt projection + softplus + clamp, transposed output (b,d,t) ----------------
__global__ __launch_bounds__(256) void dtproj_k(const float* __restrict__ x_dbl,
                                                const float* __restrict__ w,
                                                const float* __restrict__ bias,
                                                float* __restrict__ dt_t) {
  __shared__ float r_s[64][65];
  __shared__ float w_s[64][65];
  const int tid  = threadIdx.x;
  const int d0   = blockIdx.x << 6;
  const int row0 = blockIdx.y << 6;
  #pragma unroll
  for (int j = 0; j < 4; ++j) {
    int id = tid + (j << 8);          // 0..1023
    int r  = id >> 4;
    int kq = (id & 15) << 2;
    floatx4 v = *(const floatx4*)&x_dbl[(size_t)(row0 + r) * NPROJ + kq];
    r_s[r][kq] = v[0]; r_s[r][kq + 1] = v[1]; r_s[r][kq + 2] = v[2]; r_s[r][kq + 3] = v[3];
    floatx4 ww = *(const floatx4*)&w[(size_t)(d0 + r) * 64 + kq];
    w_s[r][kq] = ww[0]; w_s[r][kq + 1] = ww[1]; w_s[r][kq + 2] = ww[2]; w_s[r][kq + 3] = ww[3];
  }
  __syncthreads();
  const int tl = tid & 15, dl = tid >> 4;
  float acc[4][4] = {};               // [t][d]
  #pragma unroll 8
  for (int k = 0; k < 64; ++k) {
    float a[4], bb[4];
    #pragma unroll
    for (int i = 0; i < 4; ++i) a[i] = r_s[tl * 4 + i][k];
    #pragma unroll
    for (int j = 0; j < 4; ++j) bb[j] = w_s[dl + (j << 4)][k];
    #pragma unroll
    for (int i = 0; i < 4; ++i)
      #pragma unroll
      for (int j = 0; j < 4; ++j) acc[i][j] += a[i] * bb[j];
  }
  const int bb_ = row0 >> 11;
  const int tbase = (row0 & 2047) + tl * 4;
  #pragma unroll
  for (int j = 0; j < 4; ++j) {
    const int dd = d0 + dl + (j << 4);
    const float bsv = bias[dd];
    floatx4 o;
    #pragma unroll
    for (int i = 0; i < 4; ++i) {
      float v = acc[i][j] + bsv;
      float sp = (v > 20.f) ? v : __logf(1.f + __expf(v));
      o[i] = fminf(sp, 10.f);
    }
    *(floatx4*)&dt_t[((size_t)bb_ * DINNER + dd) * SEQLEN + tbase] = o;
  }
}

// ---------------- chunked selective scan ----------------
// Pass A: per-chunk local scan from h=0 -> final local state + chunk decay P
__global__ __launch_bounds__(256) void scanA_k(const float* __restrict__ dt_t,
                                               const float* __restrict__ u_dtl,
                                               const float* __restrict__ x_dbl,
                                               const float* __restrict__ A_log,
                                               float* __restrict__ hfin,
                                               float* __restrict__ Pbuf) {
  __shared__ float dtc[16][68];
  __shared__ float uc[16][68];
  __shared__ float Bc[TCC][20];
  const int tid = threadIdx.x;
  const int b = blockIdx.z;
  const int c = blockIdx.y;
  const int d0 = blockIdx.x << 4;
  const int s = tid & 15, ch = tid >> 4;
  const int d = d0 + ch;
  const float Av = -__expf(A_log[d * DSTATE + s]);
  const int t0 = c * TCC;
  {
    int c2 = tid >> 4, tq = (tid & 15) << 2;
    *(floatx4*)&dtc[c2][tq] = *(const floatx4*)&dt_t[((size_t)b * DINNER + d0 + c2) * SEQLEN + t0 + tq];
    *(floatx4*)&uc[c2][tq]  = *(const floatx4*)&u_dtl[((size_t)b * DINNER + d0 + c2) * SEQLEN + t0 + tq];
    int t = tid >> 2, sq = (tid & 3) << 2;
    *(floatx4*)&Bc[t][sq] = *(const floatx4*)&x_dbl[((size_t)b * SEQLEN + t0 + t) * NPROJ + 64 + sq];
  }
  __syncthreads();
  float h = 0.f, sdt = 0.f;
  #pragma unroll 8
  for (int t = 0; t < TCC; ++t) {
    const float dtv = dtc[ch][t];
    const float uv  = uc[ch][t];
    const float dA  = __expf(dtv * Av);
    h = dA * h + (dtv * uv) * Bc[t][s];
    sdt += dtv;
  }
  const float P = __expf(Av * sdt);
  const size_t idx = (((size_t)b * NCHUNK + c) * DINNER + d) * DSTATE + s;
  hfin[idx] = h;
  Pbuf[idx] = P;
}

// Pass B: serial combine over chunks -> incoming state per chunk
__global__ __launch_bounds__(256) void scanB_k(const float* __restrict__ hfin,
                                               const float* __restrict__ Pbuf,
                                               float* __restrict__ hin) {
  const int flat = blockIdx.x * 256 + threadIdx.x;   // 0..65535
  const int b  = flat >> 15;
  const int ds = flat & 32767;
  float h = 0.f;
  hin[((size_t)b * NCHUNK) * 32768 + ds] = 0.f;
  for (int c = 1; c < NCHUNK; ++c) {
    const size_t prev = ((size_t)b * NCHUNK + c - 1) * 32768 + ds;
    h = hfin[prev] + Pbuf[prev] * h;
    hin[((size_t)b * NCHUNK + c) * 32768 + ds] = h;
  }
}

// Pass C: per-chunk scan with known incoming state, y + fused gate -> bf16
__global__ __launch_bounds__(256) void scanC_k(const float* __restrict__ dt_t,
                                               const float* __restrict__ u_dtl,
                                               const float* __restrict__ x_dbl,
                                               const float* __restrict__ A_log,
                                               const float* __restrict__ Dp,
                                               const float* __restrict__ hin,
                                               const bf16* __restrict__ xr,
                                               bf16* __restrict__ yres) {
  __shared__ float dtc[16][68];
  __shared__ float uc[16][68];
  __shared__ float Bc[TCC][20];
  __shared__ float Cc[TCC][20];
  __shared__ float ytile[TCC][17];
  const int tid = threadIdx.x;
  const int b = blockIdx.z;
  const int c = blockIdx.y;
  const int d0 = blockIdx.x << 4;
  const int s = tid & 15, ch = tid >> 4;
  const int d = d0 + ch;
  const float Av = -__expf(A_log[d * DSTATE + s]);
  const float Dv = Dp[d];
  const int t0 = c * TCC;
  {
    int c2 = tid >> 4, tq = (tid & 15) << 2;
    *(floatx4*)&dtc[c2][tq] = *(const floatx4*)&dt_t[((size_t)b * DINNER + d0 + c2) * SEQLEN + t0 + tq];
    *(floatx4*)&uc[c2][tq]  = *(const floatx4*)&u_dtl[((size_t)b * DINNER + d0 + c2) * SEQLEN + t0 + tq];
    int t = tid >> 2, sq = (tid & 3) << 2;
    *(floatx4*)&Bc[t][sq] = *(const floatx4*)&x_dbl[((size_t)b * SEQLEN + t0 + t) * NPROJ + 64 + sq];
    *(floatx4*)&Cc[t][sq] = *(const floatx4*)&x_dbl[((size_t)b * SEQLEN + t0 + t) * NPROJ + 80 + sq];
  }
  float h = hin[(((size_t)b * NCHUNK + c) * DINNER + d) * DSTATE + s];
  __syncthreads();
  #pragma unroll 4
  for (int t = 0; t < TCC; ++t) {
    const float dtv = dtc[ch][t];
    const float uv  = uc[ch][t];
    const float dA  = __expf(dtv * Av);
    h = dA * h + (dtv * uv) * Bc[t][s];
    float yp = h * Cc[t][s];
    yp += __shfl_xor(yp, 1, 16);
    yp += __shfl_xor(yp, 2, 16);
    yp += __shfl_xor(yp, 4, 16);
    yp += __shfl_xor(yp, 8, 16);
    if (s == 0) ytile[t][ch] = yp + Dv * uv;
  }
  __syncthreads();
  {
    const int t  = tid >> 2;
    const int dl = (tid & 3) << 2;
    bf16x4 rv = *(const bf16x4*)&xr[((size_t)b * SEQLEN + t0 + t) * 4096 + 2048 + d0 + dl];
    bf16x4 o;
    #pragma unroll
    for (int i = 0; i < 4; ++i) {
      const float yv = ytile[t][dl + i];
      const float r  = (float)rv[i];
      o[i] = (bf16)(yv * siluf_(r));
    }
    *(bf16x4*)&yres[((size_t)b * SEQLEN + t0 + t) * DINNER + d0 + dl] = o;
  }
}

extern "C" void kernel_launch(void* const* d_in, const int* in_sizes, int n_in,
                              void* d_out, int out_size, void* d_ws, size_t ws_size,
                              hipStream_t stream) {
  const float* x         = (const float*)d_in[0];
  const float* in_proj_w = (const float*)d_in[1];
  const float* conv_w    = (const float*)d_in[2];
  const float* conv_b    = (const float*)d_in[3];
  const float* x_proj_w  = (const float*)d_in[4];
  const float* dt_proj_w = (const float*)d_in[5];
  const float* dt_proj_b = (const float*)d_in[6];
  const float* A_log     = (const float*)d_in[7];
  const float* Dp        = (const float*)d_in[8];
  const float* out_proj_w= (const float*)d_in[9];
  float* out = (float*)d_out;

  char* ws = (char*)d_ws;
  size_t off = 0;
  auto alloc = [&](size_t bytes) -> void* {
    void* p = ws + off;
    off += (bytes + 255) & ~(size_t)255;
    return p;
  };
  bf16*  x_bf   = (bf16*) alloc((size_t)NROWS * DMODEL * 2);
  bf16*  wi_bf  = (bf16*) alloc((size_t)2 * DINNER * DMODEL * 2);
  bf16*  wo_bf  = (bf16*) alloc((size_t)DMODEL * DINNER * 2);
  bf16*  xw_bf  = (bf16*) alloc((size_t)NPROJ * DINNER * 2);
  bf16*  xr     = (bf16*) alloc((size_t)NROWS * 4096 * 2);
  bf16*  u_btd  = (bf16*) alloc((size_t)NROWS * DINNER * 2);
  float* u_dtl  = (float*)alloc((size_t)BATCH * DINNER * SEQLEN * 4);
  float* x_dbl  = (float*)alloc((size_t)NROWS * NPROJ * 4);
  float* dt_t   = (float*)alloc((size_t)BATCH * DINNER * SEQLEN * 4);
  float* hfin   = (float*)alloc((size_t)BATCH * NCHUNK * DINNER * DSTATE * 4);
  float* Pbuf   = (float*)alloc((size_t)BATCH * NCHUNK * DINNER * DSTATE * 4);
  float* hin    = (float*)alloc((size_t)BATCH * NCHUNK * DINNER * DSTATE * 4);
  bf16*  yres   = (bf16*) alloc((size_t)NROWS * DINNER * 2);

  cast_bf16_k<<<(NROWS * DMODEL / 4 + 255) / 256, 256, 0, stream>>>(x, x_bf, NROWS * DMODEL / 4);
  cast_bf16_k<<<(2 * DINNER * DMODEL / 4 + 255) / 256, 256, 0, stream>>>(in_proj_w, wi_bf, 2 * DINNER * DMODEL / 4);
  cast_bf16_k<<<(DMODEL * DINNER / 4 + 255) / 256, 256, 0, stream>>>(out_proj_w, wo_bf, DMODEL * DINNER / 4);
  cast_pad_xw_k<<<NPROJ * DINNER / 4 / 256, 256, 0, stream>>>(x_proj_w, xw_bf);

  // in_proj: (4096 x 4096) = x_bf (4096x1024) @ wi_bf^T
  gemm_bt<bf16><<<dim3(32, 32), 256, 0, stream>>>(x_bf, wi_bf, xr, NROWS, 4096, DMODEL);
  // conv + SiLU
  conv_silu_k<<<dim3(DINNER / 64, SEQLEN / 32, BATCH), 256, 0, stream>>>(xr, conv_w, conv_b, u_btd, u_dtl);
  // x_proj: (4096 x 128) = u (4096x2048) @ xw^T
  gemm_bt<float><<<dim3(1, 32), 256, 0, stream>>>(u_btd, xw_bf, x_dbl, NROWS, NPROJ, DINNER);
  // dt proj + softplus + clamp -> (b,d,t)
  dtproj_k<<<dim3(DINNER / 64, NROWS / 64), 256, 0, stream>>>(x_dbl, dt_proj_w, dt_proj_b, dt_t);
  // chunked selective scan
  scanA_k<<<dim3(DINNER / 16, NCHUNK, BATCH), 256, 0, stream>>>(dt_t, u_dtl, x_dbl, A_log, hfin, Pbuf);
  scanB_k<<<dim3(BATCH * DINNER * DSTATE / 256), 256, 0, stream>>>(hfin, Pbuf, hin);
  scanC_k<<<dim3(DINNER / 16, NCHUNK, BATCH), 256, 0, stream>>>(dt_t, u_dtl, x_dbl, A_log, Dp, hin, xr, yres);
  // out_proj: (4096 x 1024) = yres (4096x2048) @ wo^T
  gemm_bt<float><<<dim3(DMODEL / 128, NROWS / 128), 256, 0, stream>>>(yres, wo_bf, out, NROWS, DMODEL, DINNER);
}

// Round 3
// 308.109 us; speedup vs baseline: 2.1254x; 1.2725x over previous
//
#include <hip/hip_runtime.h>
#include <hip/hip_bf16.h>
#include <stdint.h>

#define BATCH 2
#define SEQLEN 2048
#define DMODEL 1024
#define DINNER 2048
#define DSTATE 16
#define DTRANK 64
#define NPROJ 128            // 96 padded to 128 for the MFMA GEMM
#define NROWS (BATCH*SEQLEN) // 4096
#define NCHUNK 32
#define TCC 64               // timesteps per scan chunk

typedef __bf16 bf16;
typedef __bf16 bf16x8 __attribute__((ext_vector_type(8)));
typedef __bf16 bf16x4 __attribute__((ext_vector_type(4)));
typedef float  floatx4 __attribute__((ext_vector_type(4)));

__device__ __forceinline__ float sigmoidf_(float x) { return 1.f / (1.f + __expf(-x)); }
__device__ __forceinline__ float siluf_(float x)    { return x * sigmoidf_(x); }

__device__ __forceinline__ void gload_lds16(const void* gsrc, void* ldsdst) {
  auto g = (const __attribute__((address_space(1))) uint32_t*)(uintptr_t)gsrc;
  uint32_t lo = (uint32_t)(uintptr_t)ldsdst;
  auto l = (__attribute__((address_space(3))) uint32_t*)lo;
  __builtin_amdgcn_global_load_lds(g, l, 16, 0, 0);
}

// ---------------- casts ----------------
__global__ __launch_bounds__(256) void cast_bf16_k(const float* __restrict__ in,
                                                   bf16* __restrict__ out, int n4) {
  int i = blockIdx.x * 256 + threadIdx.x;
  if (i < n4) {
    floatx4 v = *(const floatx4*)&in[(size_t)i * 4];
    bf16x4 o;
    #pragma unroll
    for (int j = 0; j < 4; ++j) o[j] = (bf16)v[j];
    *(bf16x4*)&out[(size_t)i * 4] = o;
  }
}

// x_proj_w (96x2048) -> bf16 (128x2048), rows 96..127 zero
__global__ __launch_bounds__(256) void cast_pad_xw_k(const float* __restrict__ in,
                                                     bf16* __restrict__ out) {
  int i = blockIdx.x * 256 + threadIdx.x;   // 65536 threads, 4 elems each
  int idx = i * 4;
  int row = idx >> 11;
  bf16x4 o;
  if (row < 96) {
    floatx4 v = *(const floatx4*)&in[idx];
    #pragma unroll
    for (int j = 0; j < 4; ++j) o[j] = (bf16)v[j];
  } else {
    #pragma unroll
    for (int j = 0; j < 4; ++j) o[j] = (bf16)0.f;
  }
  *(bf16x4*)&out[idx] = o;
}

// ---------------- bf16 NT GEMM (m97 structure): C[M,N] = A[M,K] * B[N,K]^T ----------------
template <typename OT>
__global__ __launch_bounds__(256) void gemm_bt(const bf16* __restrict__ A,
                                               const bf16* __restrict__ Bm,
                                               OT* __restrict__ C,
                                               int M, int N, int K) {
  __shared__ bf16 As[128 * 32];
  __shared__ bf16 Bs[128 * 32];
  const int tid  = threadIdx.x;
  const int lane = tid & 63;
  const int wave = tid >> 6;
  const int bm = blockIdx.y * 128;
  const int bn = blockIdx.x * 128;
  const int wr = (wave >> 1) << 6;
  const int wc = (wave & 1) << 6;
  const int fr = lane & 15;
  const int fq = lane >> 4;

  const int srow  = tid >> 2;         // 0..63
  const int skoff = (tid & 3) << 3;   // 0,8,16,24 (bf16 elems)
  const bf16* ga0 = A  + (size_t)(bm + srow) * K + skoff;
  const bf16* ga1 = A  + (size_t)(bm + 64 + srow) * K + skoff;
  const bf16* gb0 = Bm + (size_t)(bn + srow) * K + skoff;
  const bf16* gb1 = Bm + (size_t)(bn + 64 + srow) * K + skoff;
  char* la0 = (char*)As + (wave << 10);
  char* la1 = (char*)As + 4096 + (wave << 10);
  char* lb0 = (char*)Bs + (wave << 10);
  char* lb1 = (char*)Bs + 4096 + (wave << 10);

  floatx4 acc[4][4];
  #pragma unroll
  for (int i = 0; i < 4; ++i)
    #pragma unroll
    for (int j = 0; j < 4; ++j)
      #pragma unroll
      for (int r = 0; r < 4; ++r) acc[i][j][r] = 0.f;

  for (int k0 = 0; k0 < K; k0 += 32) {
    gload_lds16(ga0 + k0, la0);
    gload_lds16(ga1 + k0, la1);
    gload_lds16(gb0 + k0, lb0);
    gload_lds16(gb1 + k0, lb1);
    __syncthreads();
    bf16x8 af[4], bfr[4];
    #pragma unroll
    for (int i = 0; i < 4; ++i)
      af[i] = *(const bf16x8*)&As[(wr + (i << 4) + fr) * 32 + (fq << 3)];
    #pragma unroll
    for (int j = 0; j < 4; ++j)
      bfr[j] = *(const bf16x8*)&Bs[(wc + (j << 4) + fr) * 32 + (fq << 3)];
    #pragma unroll
    for (int i = 0; i < 4; ++i)
      #pragma unroll
      for (int j = 0; j < 4; ++j)
        acc[i][j] = __builtin_amdgcn_mfma_f32_16x16x32_bf16(af[i], bfr[j], acc[i][j], 0, 0, 0);
    __syncthreads();
  }
  #pragma unroll
  for (int i = 0; i < 4; ++i) {
    const int row = bm + wr + (i << 4) + (fq << 2);
    #pragma unroll
    for (int j = 0; j < 4; ++j) {
      const int col = bn + wc + (j << 4) + fr;
      #pragma unroll
      for (int r = 0; r < 4; ++r)
        C[(size_t)(row + r) * N + col] = (OT)acc[i][j][r];
    }
  }
}

// ---------------- depthwise causal conv(4) + bias + SiLU ----------------
__global__ __launch_bounds__(256) void conv_silu_k(const bf16* __restrict__ xr,
                                                   const float* __restrict__ cw,
                                                   const float* __restrict__ cb,
                                                   bf16* __restrict__ u_btd,
                                                   float* __restrict__ u_dtl) {
  __shared__ float tile[32][65];
  const int tid = threadIdx.x;
  const int d0 = blockIdx.x << 6;   // 64 channels per block
  const int t0 = blockIdx.y << 5;   // 32 timesteps per block
  const int b  = blockIdx.z;
  const int dl = tid & 63, tq = tid >> 6;
  const int d  = d0 + dl;
  const float w0 = cw[d * 4 + 0], w1 = cw[d * 4 + 1], w2 = cw[d * 4 + 2], w3 = cw[d * 4 + 3];
  const float bias = cb[d];
  #pragma unroll
  for (int i = 0; i < 8; ++i) {
    const int t = tq * 8 + i;       // 0..31
    const int tg = t0 + t;
    float acc = bias;
    {
      int tt = tg - 3;
      if (tt >= 0) acc += w0 * (float)xr[((size_t)b * SEQLEN + tt) * 4096 + d];
    }
    {
      int tt = tg - 2;
      if (tt >= 0) acc += w1 * (float)xr[((size_t)b * SEQLEN + tt) * 4096 + d];
    }
    {
      int tt = tg - 1;
      if (tt >= 0) acc += w2 * (float)xr[((size_t)b * SEQLEN + tt) * 4096 + d];
    }
    acc += w3 * (float)xr[((size_t)b * SEQLEN + tg) * 4096 + d];
    const float uval = siluf_(acc);
    u_btd[((size_t)b * SEQLEN + tg) * DINNER + d] = (bf16)uval;
    tile[t][dl] = uval;
  }
  __syncthreads();
  const int dr = tid >> 2;            // 0..63
  const int tcol = (tid & 3) << 3;    // 0,8,16,24
  float vals[8];
  #pragma unroll
  for (int i = 0; i < 8; ++i) vals[i] = tile[tcol + i][dr];
  #pragma unroll
  for (int i = 0; i < 8; ++i)
    u_dtl[((size_t)b * DINNER + d0 + dr) * SEQLEN + t0 + tcol + i] = vals[i];
}

// ---------------- dt projection + softplus + clamp, transposed output (b,d,t) ----------------
__global__ __launch_bounds__(256) void dtproj_k(const float* __restrict__ x_dbl,
                                                const float* __restrict__ w,
                                                const float* __restrict__ bias,
                                                float* __restrict__ dt_t) {
  __shared__ float r_s[64][65];
  __shared__ float w_s[64][65];
  const int tid  = threadIdx.x;
  const int d0   = blockIdx.x << 6;
  const int row0 = blockIdx.y << 6;
  #pragma unroll
  for (int j = 0; j < 4; ++j) {
    int id = tid + (j << 8);          // 0..1023
    int r  = id >> 4;
    int kq = (id & 15) << 2;
    floatx4 v = *(const floatx4*)&x_dbl[(size_t)(row0 + r) * NPROJ + kq];
    r_s[r][kq] = v[0]; r_s[r][kq + 1] = v[1]; r_s[r][kq + 2] = v[2]; r_s[r][kq + 3] = v[3];
    floatx4 ww = *(const floatx4*)&w[(size_t)(d0 + r) * 64 + kq];
    w_s[r][kq] = ww[0]; w_s[r][kq + 1] = ww[1]; w_s[r][kq + 2] = ww[2]; w_s[r][kq + 3] = ww[3];
  }
  __syncthreads();
  const int tl = tid & 15, dl = tid >> 4;
  float acc[4][4] = {};               // [t][d]
  #pragma unroll 8
  for (int k = 0; k < 64; ++k) {
    float a[4], bb[4];
    #pragma unroll
    for (int i = 0; i < 4; ++i) a[i] = r_s[tl * 4 + i][k];
    #pragma unroll
    for (int j = 0; j < 4; ++j) bb[j] = w_s[dl + (j << 4)][k];
    #pragma unroll
    for (int i = 0; i < 4; ++i)
      #pragma unroll
      for (int j = 0; j < 4; ++j) acc[i][j] += a[i] * bb[j];
  }
  const int bb_ = row0 >> 11;
  const int tbase = (row0 & 2047) + tl * 4;
  #pragma unroll
  for (int j = 0; j < 4; ++j) {
    const int dd = d0 + dl + (j << 4);
    const float bsv = bias[dd];
    floatx4 o;
    #pragma unroll
    for (int i = 0; i < 4; ++i) {
      float v = acc[i][j] + bsv;
      float sp = (v > 20.f) ? v : __logf(1.f + __expf(v));
      o[i] = fminf(sp, 10.f);
    }
    *(floatx4*)&dt_t[((size_t)bb_ * DINNER + dd) * SEQLEN + tbase] = o;
  }
}

// ---------------- chunked selective scan, registers-own-s layout ----------------
// Pass A: per-chunk local scan from h=0 -> final local state + chunk decay P.
// One thread owns one (b, d, chunk): 16 states in registers, no cross-lane ops.
__global__ __launch_bounds__(256) void scanA_k(const float* __restrict__ dt_t,
                                               const float* __restrict__ u_dtl,
                                               const float* __restrict__ x_dbl,
                                               const float* __restrict__ A_log,
                                               float* __restrict__ hfin,
                                               float* __restrict__ Pbuf) {
  __shared__ float Bs_[TCC][16];
  const int tid = threadIdx.x;
  const int b = blockIdx.z, c = blockIdx.y;
  const int d = (blockIdx.x << 8) + tid;
  const int t0 = c * TCC;
  {
    const int t = tid >> 2, sq = (tid & 3) << 2;
    *(floatx4*)&Bs_[t][sq] = *(const floatx4*)&x_dbl[((size_t)b * SEQLEN + t0 + t) * NPROJ + 64 + sq];
  }
  float A_[DSTATE];
  #pragma unroll
  for (int q = 0; q < 4; ++q) {
    floatx4 al = *(const floatx4*)&A_log[d * DSTATE + q * 4];
    #pragma unroll
    for (int j = 0; j < 4; ++j) A_[q * 4 + j] = -__expf(al[j]);
  }
  __syncthreads();
  float h[DSTATE];
  #pragma unroll
  for (int s = 0; s < DSTATE; ++s) h[s] = 0.f;
  float sdt = 0.f;
  const float* dtp = dt_t + ((size_t)b * DINNER + d) * SEQLEN + t0;
  const float* up  = u_dtl + ((size_t)b * DINNER + d) * SEQLEN + t0;
  for (int tq = 0; tq < TCC; tq += 4) {
    floatx4 dt4 = *(const floatx4*)&dtp[tq];
    floatx4 u4  = *(const floatx4*)&up[tq];
    #pragma unroll
    for (int j = 0; j < 4; ++j) {
      const float dtv = dt4[j];
      const float xin = dtv * u4[j];
      sdt += dtv;
      floatx4 Brow[4];
      #pragma unroll
      for (int q = 0; q < 4; ++q) Brow[q] = *(const floatx4*)&Bs_[tq + j][q * 4];
      #pragma unroll
      for (int s = 0; s < DSTATE; ++s)
        h[s] = __expf(dtv * A_[s]) * h[s] + xin * Brow[s >> 2][s & 3];
    }
  }
  const size_t base = (((size_t)b * NCHUNK + c) * DINNER + d) * DSTATE;
  #pragma unroll
  for (int q = 0; q < 4; ++q) {
    floatx4 hv, pv;
    #pragma unroll
    for (int j = 0; j < 4; ++j) {
      hv[j] = h[q * 4 + j];
      pv[j] = __expf(A_[q * 4 + j] * sdt);
    }
    *(floatx4*)&hfin[base + q * 4] = hv;
    *(floatx4*)&Pbuf[base + q * 4] = pv;
  }
}

// Pass B: serial combine over chunks -> incoming state per chunk
__global__ __launch_bounds__(256) void scanB_k(const float* __restrict__ hfin,
                                               const float* __restrict__ Pbuf,
                                               float* __restrict__ hin) {
  const int flat = blockIdx.x * 256 + threadIdx.x;   // 0..65535
  const int b  = flat >> 15;
  const int ds = flat & 32767;
  float h = 0.f;
  hin[((size_t)b * NCHUNK) * 32768 + ds] = 0.f;
  for (int c = 1; c < NCHUNK; ++c) {
    const size_t prev = ((size_t)b * NCHUNK + c - 1) * 32768 + ds;
    h = hfin[prev] + Pbuf[prev] * h;
    hin[((size_t)b * NCHUNK + c) * 32768 + ds] = h;
  }
}

// Pass C: per-chunk scan with known incoming state, y + fused gate -> bf16.
// Registers-own-s: in-thread s-reduction, coalesced per-t res load / yres store.
__global__ __launch_bounds__(256) void scanC_k(const float* __restrict__ dt_t,
                                               const float* __restrict__ u_dtl,
                                               const float* __restrict__ x_dbl,
                                               const float* __restrict__ A_log,
                                               const float* __restrict__ Dp,
                                               const float* __restrict__ hin,
                                               const bf16* __restrict__ xr,
                                               bf16* __restrict__ yres) {
  __shared__ float Bs_[TCC][16];
  __shared__ float Cs_[TCC][16];
  const int tid = threadIdx.x;
  const int b = blockIdx.z, c = blockIdx.y;
  const int d = (blockIdx.x << 8) + tid;
  const int t0 = c * TCC;
  {
    const int t = tid >> 2, sq = (tid & 3) << 2;
    *(floatx4*)&Bs_[t][sq] = *(const floatx4*)&x_dbl[((size_t)b * SEQLEN + t0 + t) * NPROJ + 64 + sq];
    *(floatx4*)&Cs_[t][sq] = *(const floatx4*)&x_dbl[((size_t)b * SEQLEN + t0 + t) * NPROJ + 80 + sq];
  }
  float A_[DSTATE];
  #pragma unroll
  for (int q = 0; q < 4; ++q) {
    floatx4 al = *(const floatx4*)&A_log[d * DSTATE + q * 4];
    #pragma unroll
    for (int j = 0; j < 4; ++j) A_[q * 4 + j] = -__expf(al[j]);
  }
  float h[DSTATE];
  const size_t base = (((size_t)b * NCHUNK + c) * DINNER + d) * DSTATE;
  #pragma unroll
  for (int q = 0; q < 4; ++q) {
    floatx4 hv = *(const floatx4*)&hin[base + q * 4];
    #pragma unroll
    for (int j = 0; j < 4; ++j) h[q * 4 + j] = hv[j];
  }
  const float Dv = Dp[d];
  __syncthreads();
  const float* dtp = dt_t + ((size_t)b * DINNER + d) * SEQLEN + t0;
  const float* up  = u_dtl + ((size_t)b * DINNER + d) * SEQLEN + t0;
  const bf16* resp = xr + ((size_t)b * SEQLEN + t0) * 4096 + 2048 + d;
  bf16* yp = yres + ((size_t)b * SEQLEN + t0) * DINNER + d;
  for (int tq = 0; tq < TCC; tq += 4) {
    floatx4 dt4 = *(const floatx4*)&dtp[tq];
    floatx4 u4  = *(const floatx4*)&up[tq];
    #pragma unroll
    for (int j = 0; j < 4; ++j) {
      const int t = tq + j;
      const float dtv = dt4[j];
      const float uv  = u4[j];
      const float xin = dtv * uv;
      float acc = Dv * uv;
      floatx4 Brow[4], Crow[4];
      #pragma unroll
      for (int q = 0; q < 4; ++q) {
        Brow[q] = *(const floatx4*)&Bs_[t][q * 4];
        Crow[q] = *(const floatx4*)&Cs_[t][q * 4];
      }
      #pragma unroll
      for (int s = 0; s < DSTATE; ++s) {
        h[s] = __expf(dtv * A_[s]) * h[s] + xin * Brow[s >> 2][s & 3];
        acc += h[s] * Crow[s >> 2][s & 3];
      }
      const float r = (float)resp[(size_t)t * 4096];
      yp[(size_t)t * DINNER] = (bf16)(acc * siluf_(r));
    }
  }
}

extern "C" void kernel_launch(void* const* d_in, const int* in_sizes, int n_in,
                              void* d_out, int out_size, void* d_ws, size_t ws_size,
                              hipStream_t stream) {
  const float* x         = (const float*)d_in[0];
  const float* in_proj_w = (const float*)d_in[1];
  const float* conv_w    = (const float*)d_in[2];
  const float* conv_b    = (const float*)d_in[3];
  const float* x_proj_w  = (const float*)d_in[4];
  const float* dt_proj_w = (const float*)d_in[5];
  const float* dt_proj_b = (const float*)d_in[6];
  const float* A_log     = (const float*)d_in[7];
  const float* Dp        = (const float*)d_in[8];
  const float* out_proj_w= (const float*)d_in[9];
  float* out = (float*)d_out;

  char* ws = (char*)d_ws;
  size_t off = 0;
  auto alloc = [&](size_t bytes) -> void* {
    void* p = ws + off;
    off += (bytes + 255) & ~(size_t)255;
    return p;
  };
  bf16*  x_bf   = (bf16*) alloc((size_t)NROWS * DMODEL * 2);
  bf16*  wi_bf  = (bf16*) alloc((size_t)2 * DINNER * DMODEL * 2);
  bf16*  wo_bf  = (bf16*) alloc((size_t)DMODEL * DINNER * 2);
  bf16*  xw_bf  = (bf16*) alloc((size_t)NPROJ * DINNER * 2);
  bf16*  xr     = (bf16*) alloc((size_t)NROWS * 4096 * 2);
  bf16*  u_btd  = (bf16*) alloc((size_t)NROWS * DINNER * 2);
  float* u_dtl  = (float*)alloc((size_t)BATCH * DINNER * SEQLEN * 4);
  float* x_dbl  = (float*)alloc((size_t)NROWS * NPROJ * 4);
  float* dt_t   = (float*)alloc((size_t)BATCH * DINNER * SEQLEN * 4);
  float* hfin   = (float*)alloc((size_t)BATCH * NCHUNK * DINNER * DSTATE * 4);
  float* Pbuf   = (float*)alloc((size_t)BATCH * NCHUNK * DINNER * DSTATE * 4);
  float* hin    = (float*)alloc((size_t)BATCH * NCHUNK * DINNER * DSTATE * 4);
  bf16*  yres   = (bf16*) alloc((size_t)NROWS * DINNER * 2);

  cast_bf16_k<<<(NROWS * DMODEL / 4 + 255) / 256, 256, 0, stream>>>(x, x_bf, NROWS * DMODEL / 4);
  cast_bf16_k<<<(2 * DINNER * DMODEL / 4 + 255) / 256, 256, 0, stream>>>(in_proj_w, wi_bf, 2 * DINNER * DMODEL / 4);
  cast_bf16_k<<<(DMODEL * DINNER / 4 + 255) / 256, 256, 0, stream>>>(out_proj_w, wo_bf, DMODEL * DINNER / 4);
  cast_pad_xw_k<<<NPROJ * DINNER / 4 / 256, 256, 0, stream>>>(x_proj_w, xw_bf);

  // in_proj: (4096 x 4096) = x_bf (4096x1024) @ wi_bf^T
  gemm_bt<bf16><<<dim3(32, 32), 256, 0, stream>>>(x_bf, wi_bf, xr, NROWS, 4096, DMODEL);
  // conv + SiLU
  conv_silu_k<<<dim3(DINNER / 64, SEQLEN / 32, BATCH), 256, 0, stream>>>(xr, conv_w, conv_b, u_btd, u_dtl);
  // x_proj: (4096 x 128) = u (4096x2048) @ xw^T
  gemm_bt<float><<<dim3(1, 32), 256, 0, stream>>>(u_btd, xw_bf, x_dbl, NROWS, NPROJ, DINNER);
  // dt proj + softplus + clamp -> (b,d,t)
  dtproj_k<<<dim3(DINNER / 64, NROWS / 64), 256, 0, stream>>>(x_dbl, dt_proj_w, dt_proj_b, dt_t);
  // chunked selective scan (registers-own-s)
  scanA_k<<<dim3(DINNER / 256, NCHUNK, BATCH), 256, 0, stream>>>(dt_t, u_dtl, x_dbl, A_log, hfin, Pbuf);
  scanB_k<<<dim3(BATCH * DINNER * DSTATE / 256), 256, 0, stream>>>(hfin, Pbuf, hin);
  scanC_k<<<dim3(DINNER / 256, NCHUNK, BATCH), 256, 0, stream>>>(dt_t, u_dtl, x_dbl, A_log, Dp, hin, xr, yres);
  // out_proj: (4096 x 1024) = yres (4096x2048) @ wo^T
  gemm_bt<float><<<dim3(DMODEL / 128, NROWS / 128), 256, 0, stream>>>(yres, wo_bf, out, NROWS, DMODEL, DINNER);
}

// Round 4
// 280.431 us; speedup vs baseline: 2.3351x; 1.0987x over previous
//
#include <hip/hip_runtime.h>
#include <hip/hip_bf16.h>
#include <stdint.h>

#define BATCH 2
#define SEQLEN 2048
#define DMODEL 1024
#define DINNER 2048
#define DSTATE 16
#define DTRANK 64
#define NPROJ 128            // 96 padded to 128 for the MFMA GEMM
#define NROWS (BATCH*SEQLEN) // 4096
#define NCHUNK 32
#define TCC 64               // timesteps per scan chunk

typedef __bf16 bf16;
typedef __bf16 bf16x8 __attribute__((ext_vector_type(8)));
typedef __bf16 bf16x4 __attribute__((ext_vector_type(4)));
typedef float  floatx4 __attribute__((ext_vector_type(4)));

__device__ __forceinline__ float sigmoidf_(float x) { return 1.f / (1.f + __expf(-x)); }
__device__ __forceinline__ float siluf_(float x)    { return x * sigmoidf_(x); }

__device__ __forceinline__ void gload_lds16(const void* gsrc, void* ldsdst) {
  auto g = (const __attribute__((address_space(1))) uint32_t*)(uintptr_t)gsrc;
  uint32_t lo = (uint32_t)(uintptr_t)ldsdst;
  auto l = (__attribute__((address_space(3))) uint32_t*)lo;
  __builtin_amdgcn_global_load_lds(g, l, 16, 0, 0);
}

// bijective XCD swizzle (m204 form) on the xy-flattened block id
__device__ __forceinline__ void swz_block(int gx, int gy, int& bx, int& by) {
  const int nwg = gx * gy;
  const int flat = by * gx + bx;
  const int q = nwg >> 3, r = nwg & 7;
  const int xcd = flat & 7, lin = flat >> 3;
  const int nf = (xcd < r) ? (xcd * (q + 1) + lin)
                           : (r * (q + 1) + (xcd - r) * q + lin);
  bx = nf % gx;
  by = nf / gx;
}

// ---------------- fused casts: x, in_proj_w, out_proj_w -> bf16; x_proj_w -> bf16 padded 96->128 ----------------
#define CAST_XN   (NROWS * DMODEL)        // 4194304
#define CAST_WIN  (2 * DINNER * DMODEL)   // 8388608
#define CAST_WON  (DMODEL * DINNER)       // 2097152
#define CAST_XWN  (NPROJ * DINNER)        // 262144 (output elems)
#define CAST_TOT4 ((CAST_XN + CAST_WIN + CAST_WON + CAST_XWN) / 4)  // 3735552

__device__ __forceinline__ void cvt4(const float* in, bf16* out) {
  floatx4 v = *(const floatx4*)in;
  bf16x4 o;
  #pragma unroll
  for (int j = 0; j < 4; ++j) o[j] = (bf16)v[j];
  *(bf16x4*)out = o;
}

__global__ __launch_bounds__(256) void cast_all_k(const float* __restrict__ x,
                                                  const float* __restrict__ wi,
                                                  const float* __restrict__ wo,
                                                  const float* __restrict__ xw,
                                                  bf16* __restrict__ x_bf,
                                                  bf16* __restrict__ wi_bf,
                                                  bf16* __restrict__ wo_bf,
                                                  bf16* __restrict__ xw_bf) {
  const int i = blockIdx.x * 256 + threadIdx.x;
  const int e = i * 4;
  if (e < CAST_XN) {
    cvt4(x + e, x_bf + e);
  } else if (e < CAST_XN + CAST_WIN) {
    const int o = e - CAST_XN;
    cvt4(wi + o, wi_bf + o);
  } else if (e < CAST_XN + CAST_WIN + CAST_WON) {
    const int o = e - CAST_XN - CAST_WIN;
    cvt4(wo + o, wo_bf + o);
  } else {
    const int o = e - CAST_XN - CAST_WIN - CAST_WON;
    const int row = o >> 11;
    bf16x4 z;
    if (row < 96) {
      cvt4(xw + o, xw_bf + o);
    } else {
      #pragma unroll
      for (int j = 0; j < 4; ++j) z[j] = (bf16)0.f;
      *(bf16x4*)&xw_bf[o] = z;
    }
  }
}

// ---------------- bf16 NT GEMM (m97 structure): C[M,N] = A[M,K] * B[N,K]^T ----------------
template <typename OT>
__global__ __launch_bounds__(256) void gemm_bt(const bf16* __restrict__ A,
                                               const bf16* __restrict__ Bm,
                                               OT* __restrict__ C,
                                               int M, int N, int K) {
  __shared__ bf16 As[128 * 32];
  __shared__ bf16 Bs[128 * 32];
  const int tid  = threadIdx.x;
  const int lane = tid & 63;
  const int wave = tid >> 6;
  int bxs = blockIdx.x, bys = blockIdx.y;
  swz_block(gridDim.x, gridDim.y, bxs, bys);
  const int bm = bys * 128;
  const int bn = bxs * 128;
  const int wr = (wave >> 1) << 6;
  const int wc = (wave & 1) << 6;
  const int fr = lane & 15;
  const int fq = lane >> 4;

  const int srow  = tid >> 2;         // 0..63
  const int skoff = (tid & 3) << 3;   // 0,8,16,24 (bf16 elems)
  const bf16* ga0 = A  + (size_t)(bm + srow) * K + skoff;
  const bf16* ga1 = A  + (size_t)(bm + 64 + srow) * K + skoff;
  const bf16* gb0 = Bm + (size_t)(bn + srow) * K + skoff;
  const bf16* gb1 = Bm + (size_t)(bn + 64 + srow) * K + skoff;
  char* la0 = (char*)As + (wave << 10);
  char* la1 = (char*)As + 4096 + (wave << 10);
  char* lb0 = (char*)Bs + (wave << 10);
  char* lb1 = (char*)Bs + 4096 + (wave << 10);

  floatx4 acc[4][4];
  #pragma unroll
  for (int i = 0; i < 4; ++i)
    #pragma unroll
    for (int j = 0; j < 4; ++j)
      #pragma unroll
      for (int r = 0; r < 4; ++r) acc[i][j][r] = 0.f;

  for (int k0 = 0; k0 < K; k0 += 32) {
    gload_lds16(ga0 + k0, la0);
    gload_lds16(ga1 + k0, la1);
    gload_lds16(gb0 + k0, lb0);
    gload_lds16(gb1 + k0, lb1);
    __syncthreads();
    bf16x8 af[4], bfr[4];
    #pragma unroll
    for (int i = 0; i < 4; ++i)
      af[i] = *(const bf16x8*)&As[(wr + (i << 4) + fr) * 32 + (fq << 3)];
    #pragma unroll
    for (int j = 0; j < 4; ++j)
      bfr[j] = *(const bf16x8*)&Bs[(wc + (j << 4) + fr) * 32 + (fq << 3)];
    #pragma unroll
    for (int i = 0; i < 4; ++i)
      #pragma unroll
      for (int j = 0; j < 4; ++j)
        acc[i][j] = __builtin_amdgcn_mfma_f32_16x16x32_bf16(af[i], bfr[j], acc[i][j], 0, 0, 0);
    __syncthreads();
  }
  #pragma unroll
  for (int i = 0; i < 4; ++i) {
    const int row = bm + wr + (i << 4) + (fq << 2);
    #pragma unroll
    for (int j = 0; j < 4; ++j) {
      const int col = bn + wc + (j << 4) + fr;
      #pragma unroll
      for (int r = 0; r < 4; ++r)
        C[(size_t)(row + r) * N + col] = (OT)acc[i][j][r];
    }
  }
}

// ---------------- split-K variant: block z computes K-slice [z*KS, (z+1)*KS), f32 partials ----------------
__global__ __launch_bounds__(256) void gemm_bt_sk(const bf16* __restrict__ A,
                                                  const bf16* __restrict__ Bm,
                                                  float* __restrict__ Cp,
                                                  int M, int N, int ldk, int KS) {
  __shared__ bf16 As[128 * 32];
  __shared__ bf16 Bs[128 * 32];
  const int tid  = threadIdx.x;
  const int lane = tid & 63;
  const int wave = tid >> 6;
  int bxs = blockIdx.x, bys = blockIdx.y;
  swz_block(gridDim.x, gridDim.y, bxs, bys);
  const int bm = bys * 128;
  const int bn = bxs * 128;
  const int z  = blockIdx.z;
  const int wr = (wave >> 1) << 6;
  const int wc = (wave & 1) << 6;
  const int fr = lane & 15;
  const int fq = lane >> 4;

  const int srow  = tid >> 2;
  const int skoff = (tid & 3) << 3;
  const size_t kbase = (size_t)z * KS + skoff;
  const bf16* ga0 = A  + (size_t)(bm + srow) * ldk + kbase;
  const bf16* ga1 = A  + (size_t)(bm + 64 + srow) * ldk + kbase;
  const bf16* gb0 = Bm + (size_t)(bn + srow) * ldk + kbase;
  const bf16* gb1 = Bm + (size_t)(bn + 64 + srow) * ldk + kbase;
  char* la0 = (char*)As + (wave << 10);
  char* la1 = (char*)As + 4096 + (wave << 10);
  char* lb0 = (char*)Bs + (wave << 10);
  char* lb1 = (char*)Bs + 4096 + (wave << 10);

  floatx4 acc[4][4];
  #pragma unroll
  for (int i = 0; i < 4; ++i)
    #pragma unroll
    for (int j = 0; j < 4; ++j)
      #pragma unroll
      for (int r = 0; r < 4; ++r) acc[i][j][r] = 0.f;

  for (int k0 = 0; k0 < KS; k0 += 32) {
    gload_lds16(ga0 + k0, la0);
    gload_lds16(ga1 + k0, la1);
    gload_lds16(gb0 + k0, lb0);
    gload_lds16(gb1 + k0, lb1);
    __syncthreads();
    bf16x8 af[4], bfr[4];
    #pragma unroll
    for (int i = 0; i < 4; ++i)
      af[i] = *(const bf16x8*)&As[(wr + (i << 4) + fr) * 32 + (fq << 3)];
    #pragma unroll
    for (int j = 0; j < 4; ++j)
      bfr[j] = *(const bf16x8*)&Bs[(wc + (j << 4) + fr) * 32 + (fq << 3)];
    #pragma unroll
    for (int i = 0; i < 4; ++i)
      #pragma unroll
      for (int j = 0; j < 4; ++j)
        acc[i][j] = __builtin_amdgcn_mfma_f32_16x16x32_bf16(af[i], bfr[j], acc[i][j], 0, 0, 0);
    __syncthreads();
  }
  float* Cb = Cp + (size_t)z * M * N;
  #pragma unroll
  for (int i = 0; i < 4; ++i) {
    const int row = bm + wr + (i << 4) + (fq << 2);
    #pragma unroll
    for (int j = 0; j < 4; ++j) {
      const int col = bn + wc + (j << 4) + fr;
      #pragma unroll
      for (int r = 0; r < 4; ++r)
        Cb[(size_t)(row + r) * N + col] = acc[i][j][r];
    }
  }
}

// fixed-order split-K reduce -> f32 (deterministic)
template <int KS>
__global__ __launch_bounds__(256) void reduce_sk_k(const float* __restrict__ part,
                                                   float* __restrict__ out,
                                                   int n4, size_t mn) {
  const int i = blockIdx.x * 256 + threadIdx.x;
  if (i >= n4) return;
  const size_t e = (size_t)i * 4;
  floatx4 s = *(const floatx4*)&part[e];
  #pragma unroll
  for (int z = 1; z < KS; ++z) {
    floatx4 v = *(const floatx4*)&part[(size_t)z * mn + e];
    #pragma unroll
    for (int j = 0; j < 4; ++j) s[j] += v[j];
  }
  *(floatx4*)&out[e] = s;
}

// ---------------- depthwise causal conv(4) + bias + SiLU ----------------
__global__ __launch_bounds__(256) void conv_silu_k(const bf16* __restrict__ xr,
                                                   const float* __restrict__ cw,
                                                   const float* __restrict__ cb,
                                                   bf16* __restrict__ u_btd,
                                                   float* __restrict__ u_dtl) {
  __shared__ float tile[32][65];
  const int tid = threadIdx.x;
  const int d0 = blockIdx.x << 6;   // 64 channels per block
  const int t0 = blockIdx.y << 5;   // 32 timesteps per block
  const int b  = blockIdx.z;
  const int dl = tid & 63, tq = tid >> 6;
  const int d  = d0 + dl;
  const float w0 = cw[d * 4 + 0], w1 = cw[d * 4 + 1], w2 = cw[d * 4 + 2], w3 = cw[d * 4 + 3];
  const float bias = cb[d];
  #pragma unroll
  for (int i = 0; i < 8; ++i) {
    const int t = tq * 8 + i;       // 0..31
    const int tg = t0 + t;
    float acc = bias;
    {
      int tt = tg - 3;
      if (tt >= 0) acc += w0 * (float)xr[((size_t)b * SEQLEN + tt) * 4096 + d];
    }
    {
      int tt = tg - 2;
      if (tt >= 0) acc += w1 * (float)xr[((size_t)b * SEQLEN + tt) * 4096 + d];
    }
    {
      int tt = tg - 1;
      if (tt >= 0) acc += w2 * (float)xr[((size_t)b * SEQLEN + tt) * 4096 + d];
    }
    acc += w3 * (float)xr[((size_t)b * SEQLEN + tg) * 4096 + d];
    const float uval = siluf_(acc);
    u_btd[((size_t)b * SEQLEN + tg) * DINNER + d] = (bf16)uval;
    tile[t][dl] = uval;
  }
  __syncthreads();
  const int dr = tid >> 2;            // 0..63
  const int tcol = (tid & 3) << 3;    // 0,8,16,24
  float vals[8];
  #pragma unroll
  for (int i = 0; i < 8; ++i) vals[i] = tile[tcol + i][dr];
  #pragma unroll
  for (int i = 0; i < 8; ++i)
    u_dtl[((size_t)b * DINNER + d0 + dr) * SEQLEN + t0 + tcol + i] = vals[i];
}

// ---------------- dt projection + softplus + clamp, transposed output (b,d,t) ----------------
__global__ __launch_bounds__(256) void dtproj_k(const float* __restrict__ x_dbl,
                                                const float* __restrict__ w,
                                                const float* __restrict__ bias,
                                                float* __restrict__ dt_t) {
  __shared__ float r_s[64][65];
  __shared__ float w_s[64][65];
  const int tid  = threadIdx.x;
  const int d0   = blockIdx.x << 6;
  const int row0 = blockIdx.y << 6;
  #pragma unroll
  for (int j = 0; j < 4; ++j) {
    int id = tid + (j << 8);          // 0..1023
    int r  = id >> 4;
    int kq = (id & 15) << 2;
    floatx4 v = *(const floatx4*)&x_dbl[(size_t)(row0 + r) * NPROJ + kq];
    r_s[r][kq] = v[0]; r_s[r][kq + 1] = v[1]; r_s[r][kq + 2] = v[2]; r_s[r][kq + 3] = v[3];
    floatx4 ww = *(const floatx4*)&w[(size_t)(d0 + r) * 64 + kq];
    w_s[r][kq] = ww[0]; w_s[r][kq + 1] = ww[1]; w_s[r][kq + 2] = ww[2]; w_s[r][kq + 3] = ww[3];
  }
  __syncthreads();
  const int tl = tid & 15, dl = tid >> 4;
  float acc[4][4] = {};               // [t][d]
  #pragma unroll 8
  for (int k = 0; k < 64; ++k) {
    float a[4], bb[4];
    #pragma unroll
    for (int i = 0; i < 4; ++i) a[i] = r_s[tl * 4 + i][k];
    #pragma unroll
    for (int j = 0; j < 4; ++j) bb[j] = w_s[dl + (j << 4)][k];
    #pragma unroll
    for (int i = 0; i < 4; ++i)
      #pragma unroll
      for (int j = 0; j < 4; ++j) acc[i][j] += a[i] * bb[j];
  }
  const int bb_ = row0 >> 11;
  const int tbase = (row0 & 2047) + tl * 4;
  #pragma unroll
  for (int j = 0; j < 4; ++j) {
    const int dd = d0 + dl + (j << 4);
    const float bsv = bias[dd];
    floatx4 o;
    #pragma unroll
    for (int i = 0; i < 4; ++i) {
      float v = acc[i][j] + bsv;
      float sp = (v > 20.f) ? v : __logf(1.f + __expf(v));
      o[i] = fminf(sp, 10.f);
    }
    *(floatx4*)&dt_t[((size_t)bb_ * DINNER + dd) * SEQLEN + tbase] = o;
  }
}

// ---------------- chunked selective scan, registers-own-s layout ----------------
__global__ __launch_bounds__(256) void scanA_k(const float* __restrict__ dt_t,
                                               const float* __restrict__ u_dtl,
                                               const float* __restrict__ x_dbl,
                                               const float* __restrict__ A_log,
                                               float* __restrict__ hfin,
                                               float* __restrict__ Pbuf) {
  __shared__ float Bs_[TCC][16];
  const int tid = threadIdx.x;
  const int b = blockIdx.z, c = blockIdx.y;
  const int d = (blockIdx.x << 8) + tid;
  const int t0 = c * TCC;
  {
    const int t = tid >> 2, sq = (tid & 3) << 2;
    *(floatx4*)&Bs_[t][sq] = *(const floatx4*)&x_dbl[((size_t)b * SEQLEN + t0 + t) * NPROJ + 64 + sq];
  }
  float A_[DSTATE];
  #pragma unroll
  for (int q = 0; q < 4; ++q) {
    floatx4 al = *(const floatx4*)&A_log[d * DSTATE + q * 4];
    #pragma unroll
    for (int j = 0; j < 4; ++j) A_[q * 4 + j] = -__expf(al[j]);
  }
  __syncthreads();
  float h[DSTATE];
  #pragma unroll
  for (int s = 0; s < DSTATE; ++s) h[s] = 0.f;
  float sdt = 0.f;
  const float* dtp = dt_t + ((size_t)b * DINNER + d) * SEQLEN + t0;
  const float* up  = u_dtl + ((size_t)b * DINNER + d) * SEQLEN + t0;
  for (int tq = 0; tq < TCC; tq += 4) {
    floatx4 dt4 = *(const floatx4*)&dtp[tq];
    floatx4 u4  = *(const floatx4*)&up[tq];
    #pragma unroll
    for (int j = 0; j < 4; ++j) {
      const float dtv = dt4[j];
      const float xin = dtv * u4[j];
      sdt += dtv;
      floatx4 Brow[4];
      #pragma unroll
      for (int q = 0; q < 4; ++q) Brow[q] = *(const floatx4*)&Bs_[tq + j][q * 4];
      #pragma unroll
      for (int s = 0; s < DSTATE; ++s)
        h[s] = __expf(dtv * A_[s]) * h[s] + xin * Brow[s >> 2][s & 3];
    }
  }
  const size_t base = (((size_t)b * NCHUNK + c) * DINNER + d) * DSTATE;
  #pragma unroll
  for (int q = 0; q < 4; ++q) {
    floatx4 hv, pv;
    #pragma unroll
    for (int j = 0; j < 4; ++j) {
      hv[j] = h[q * 4 + j];
      pv[j] = __expf(A_[q * 4 + j] * sdt);
    }
    *(floatx4*)&hfin[base + q * 4] = hv;
    *(floatx4*)&Pbuf[base + q * 4] = pv;
  }
}

__global__ __launch_bounds__(256) void scanB_k(const float* __restrict__ hfin,
                                               const float* __restrict__ Pbuf,
                                               float* __restrict__ hin) {
  const int flat = blockIdx.x * 256 + threadIdx.x;   // 0..65535
  const int b  = flat >> 15;
  const int ds = flat & 32767;
  float h = 0.f;
  hin[((size_t)b * NCHUNK) * 32768 + ds] = 0.f;
  for (int c = 1; c < NCHUNK; ++c) {
    const size_t prev = ((size_t)b * NCHUNK + c - 1) * 32768 + ds;
    h = hfin[prev] + Pbuf[prev] * h;
    hin[((size_t)b * NCHUNK + c) * 32768 + ds] = h;
  }
}

__global__ __launch_bounds__(256) void scanC_k(const float* __restrict__ dt_t,
                                               const float* __restrict__ u_dtl,
                                               const float* __restrict__ x_dbl,
                                               const float* __restrict__ A_log,
                                               const float* __restrict__ Dp,
                                               const float* __restrict__ hin,
                                               const bf16* __restrict__ xr,
                                               bf16* __restrict__ yres) {
  __shared__ float Bs_[TCC][16];
  __shared__ float Cs_[TCC][16];
  const int tid = threadIdx.x;
  const int b = blockIdx.z, c = blockIdx.y;
  const int d = (blockIdx.x << 8) + tid;
  const int t0 = c * TCC;
  {
    const int t = tid >> 2, sq = (tid & 3) << 2;
    *(floatx4*)&Bs_[t][sq] = *(const floatx4*)&x_dbl[((size_t)b * SEQLEN + t0 + t) * NPROJ + 64 + sq];
    *(floatx4*)&Cs_[t][sq] = *(const floatx4*)&x_dbl[((size_t)b * SEQLEN + t0 + t) * NPROJ + 80 + sq];
  }
  float A_[DSTATE];
  #pragma unroll
  for (int q = 0; q < 4; ++q) {
    floatx4 al = *(const floatx4*)&A_log[d * DSTATE + q * 4];
    #pragma unroll
    for (int j = 0; j < 4; ++j) A_[q * 4 + j] = -__expf(al[j]);
  }
  float h[DSTATE];
  const size_t base = (((size_t)b * NCHUNK + c) * DINNER + d) * DSTATE;
  #pragma unroll
  for (int q = 0; q < 4; ++q) {
    floatx4 hv = *(const floatx4*)&hin[base + q * 4];
    #pragma unroll
    for (int j = 0; j < 4; ++j) h[q * 4 + j] = hv[j];
  }
  const float Dv = Dp[d];
  __syncthreads();
  const float* dtp = dt_t + ((size_t)b * DINNER + d) * SEQLEN + t0;
  const float* up  = u_dtl + ((size_t)b * DINNER + d) * SEQLEN + t0;
  const bf16* resp = xr + ((size_t)b * SEQLEN + t0) * 4096 + 2048 + d;
  bf16* yp = yres + ((size_t)b * SEQLEN + t0) * DINNER + d;
  for (int tq = 0; tq < TCC; tq += 4) {
    floatx4 dt4 = *(const floatx4*)&dtp[tq];
    floatx4 u4  = *(const floatx4*)&up[tq];
    #pragma unroll
    for (int j = 0; j < 4; ++j) {
      const int t = tq + j;
      const float dtv = dt4[j];
      const float uv  = u4[j];
      const float xin = dtv * uv;
      float acc = Dv * uv;
      floatx4 Brow[4], Crow[4];
      #pragma unroll
      for (int q = 0; q < 4; ++q) {
        Brow[q] = *(const floatx4*)&Bs_[t][q * 4];
        Crow[q] = *(const floatx4*)&Cs_[t][q * 4];
      }
      #pragma unroll
      for (int s = 0; s < DSTATE; ++s) {
        h[s] = __expf(dtv * A_[s]) * h[s] + xin * Brow[s >> 2][s & 3];
        acc += h[s] * Crow[s >> 2][s & 3];
      }
      const float r = (float)resp[(size_t)t * 4096];
      yp[(size_t)t * DINNER] = (bf16)(acc * siluf_(r));
    }
  }
}

extern "C" void kernel_launch(void* const* d_in, const int* in_sizes, int n_in,
                              void* d_out, int out_size, void* d_ws, size_t ws_size,
                              hipStream_t stream) {
  const float* x         = (const float*)d_in[0];
  const float* in_proj_w = (const float*)d_in[1];
  const float* conv_w    = (const float*)d_in[2];
  const float* conv_b    = (const float*)d_in[3];
  const float* x_proj_w  = (const float*)d_in[4];
  const float* dt_proj_w = (const float*)d_in[5];
  const float* dt_proj_b = (const float*)d_in[6];
  const float* A_log     = (const float*)d_in[7];
  const float* Dp        = (const float*)d_in[8];
  const float* out_proj_w= (const float*)d_in[9];
  float* out = (float*)d_out;

  char* ws = (char*)d_ws;
  size_t off = 0;
  auto alloc = [&](size_t bytes) -> void* {
    void* p = ws + off;
    off += (bytes + 255) & ~(size_t)255;
    return p;
  };
  // long-lived buffers first
  bf16*  wo_bf  = (bf16*) alloc((size_t)DMODEL * DINNER * 2);
  bf16*  xw_bf  = (bf16*) alloc((size_t)NPROJ * DINNER * 2);
  bf16*  yres   = (bf16*) alloc((size_t)NROWS * DINNER * 2);
  float* x_dbl  = (float*)alloc((size_t)NROWS * NPROJ * 4);
  float* dt_t   = (float*)alloc((size_t)BATCH * DINNER * SEQLEN * 4);
  float* u_dtl  = (float*)alloc((size_t)BATCH * DINNER * SEQLEN * 4);
  float* hfin   = (float*)alloc((size_t)BATCH * NCHUNK * DINNER * DSTATE * 4);
  float* Pbuf   = (float*)alloc((size_t)BATCH * NCHUNK * DINNER * DSTATE * 4);
  float* hin    = (float*)alloc((size_t)BATCH * NCHUNK * DINNER * DSTATE * 4);
  // overlay region: early-dead buffers, later reused for split-K partials
  const size_t mark = off;
  bf16*  x_bf   = (bf16*) alloc((size_t)NROWS * DMODEL * 2);      // dead after in_proj
  bf16*  wi_bf  = (bf16*) alloc((size_t)2 * DINNER * DMODEL * 2); // dead after in_proj
  bf16*  xr     = (bf16*) alloc((size_t)NROWS * 4096 * 2);        // dead after scanC
  bf16*  u_btd  = (bf16*) alloc((size_t)NROWS * DINNER * 2);      // dead after x_proj
  // xpart (16.8 MB) aliases x_bf+wi_bf (25.2 MB, dead by x_proj time)
  float* xpart  = (float*)(ws + mark);
  // opart (67 MB) aliases x_bf..u_btd (75.5 MB, all dead by out_proj time)
  float* opart  = (float*)(ws + mark);

  // fused casts (1 launch)
  cast_all_k<<<CAST_TOT4 / 256, 256, 0, stream>>>(x, in_proj_w, out_proj_w, x_proj_w,
                                                  x_bf, wi_bf, wo_bf, xw_bf);
  // in_proj: (4096 x 4096) = x_bf (4096x1024) @ wi_bf^T
  gemm_bt<bf16><<<dim3(32, 32), 256, 0, stream>>>(x_bf, wi_bf, xr, NROWS, 4096, DMODEL);
  // conv + SiLU
  conv_silu_k<<<dim3(DINNER / 64, SEQLEN / 32, BATCH), 256, 0, stream>>>(xr, conv_w, conv_b, u_btd, u_dtl);
  // x_proj: (4096 x 128) = u (4096x2048) @ xw^T, split-K x8
  gemm_bt_sk<<<dim3(1, 32, 8), 256, 0, stream>>>(u_btd, xw_bf, xpart, NROWS, NPROJ, DINNER, DINNER / 8);
  reduce_sk_k<8><<<(NROWS * NPROJ / 4 + 255) / 256, 256, 0, stream>>>(xpart, x_dbl, NROWS * NPROJ / 4, (size_t)NROWS * NPROJ);
  // dt proj + softplus + clamp -> (b,d,t)
  dtproj_k<<<dim3(DINNER / 64, NROWS / 64), 256, 0, stream>>>(x_dbl, dt_proj_w, dt_proj_b, dt_t);
  // chunked selective scan (registers-own-s)
  scanA_k<<<dim3(DINNER / 256, NCHUNK, BATCH), 256, 0, stream>>>(dt_t, u_dtl, x_dbl, A_log, hfin, Pbuf);
  scanB_k<<<dim3(BATCH * DINNER * DSTATE / 256), 256, 0, stream>>>(hfin, Pbuf, hin);
  scanC_k<<<dim3(DINNER / 256, NCHUNK, BATCH), 256, 0, stream>>>(dt_t, u_dtl, x_dbl, A_log, Dp, hin, xr, yres);
  // out_proj: (4096 x 1024) = yres (4096x2048) @ wo^T, split-K x4
  gemm_bt_sk<<<dim3(DMODEL / 128, NROWS / 128, 4), 256, 0, stream>>>(yres, wo_bf, opart, NROWS, DMODEL, DINNER, DINNER / 4);
  reduce_sk_k<4><<<(NROWS * DMODEL / 4 + 255) / 256, 256, 0, stream>>>(opart, out, NROWS * DMODEL / 4, (size_t)NROWS * DMODEL);
}

// Round 5
// 264.646 us; speedup vs baseline: 2.4744x; 1.0596x over previous
//
#include <hip/hip_runtime.h>
#include <hip/hip_bf16.h>
#include <stdint.h>

#define BATCH 2
#define SEQLEN 2048
#define DMODEL 1024
#define DINNER 2048
#define DSTATE 16
#define DTRANK 64
#define NPROJ 128            // 96 padded to 128 for the MFMA GEMM
#define NROWS (BATCH*SEQLEN) // 4096
#define NCHUNK 32
#define TCC 64               // timesteps per scan chunk

typedef __bf16 bf16;
typedef __bf16 bf16x8 __attribute__((ext_vector_type(8)));
typedef __bf16 bf16x4 __attribute__((ext_vector_type(4)));
typedef float  floatx4 __attribute__((ext_vector_type(4)));

__device__ __forceinline__ float sigmoidf_(float x) { return 1.f / (1.f + __expf(-x)); }
__device__ __forceinline__ float siluf_(float x)    { return x * sigmoidf_(x); }

__device__ __forceinline__ void gload_lds16(const void* gsrc, void* ldsdst) {
  auto g = (const __attribute__((address_space(1))) uint32_t*)(uintptr_t)gsrc;
  uint32_t lo = (uint32_t)(uintptr_t)ldsdst;
  auto l = (__attribute__((address_space(3))) uint32_t*)lo;
  __builtin_amdgcn_global_load_lds(g, l, 16, 0, 0);
}

// ---------------- fused casts: x, in_proj_w, out_proj_w -> bf16; x_proj_w -> bf16 padded 96->128 ----------------
#define CAST_XN   (NROWS * DMODEL)        // 4194304
#define CAST_WIN  (2 * DINNER * DMODEL)   // 8388608
#define CAST_WON  (DMODEL * DINNER)       // 2097152
#define CAST_XWN  (NPROJ * DINNER)        // 262144 (output elems)
#define CAST_TOT4 ((CAST_XN + CAST_WIN + CAST_WON + CAST_XWN) / 4)  // 3735552

__device__ __forceinline__ void cvt4(const float* in, bf16* out) {
  floatx4 v = *(const floatx4*)in;
  bf16x4 o;
  #pragma unroll
  for (int j = 0; j < 4; ++j) o[j] = (bf16)v[j];
  *(bf16x4*)out = o;
}

__global__ __launch_bounds__(256) void cast_all_k(const float* __restrict__ x,
                                                  const float* __restrict__ wi,
                                                  const float* __restrict__ wo,
                                                  const float* __restrict__ xw,
                                                  bf16* __restrict__ x_bf,
                                                  bf16* __restrict__ wi_bf,
                                                  bf16* __restrict__ wo_bf,
                                                  bf16* __restrict__ xw_bf) {
  const int i = blockIdx.x * 256 + threadIdx.x;
  const int e = i * 4;
  if (e < CAST_XN) {
    cvt4(x + e, x_bf + e);
  } else if (e < CAST_XN + CAST_WIN) {
    const int o = e - CAST_XN;
    cvt4(wi + o, wi_bf + o);
  } else if (e < CAST_XN + CAST_WIN + CAST_WON) {
    const int o = e - CAST_XN - CAST_WIN;
    cvt4(wo + o, wo_bf + o);
  } else {
    const int o = e - CAST_XN - CAST_WIN - CAST_WON;
    const int row = o >> 11;
    bf16x4 z;
    if (row < 96) {
      cvt4(xw + o, xw_bf + o);
    } else {
      #pragma unroll
      for (int j = 0; j < 4; ++j) z[j] = (bf16)0.f;
      *(bf16x4*)&xw_bf[o] = z;
    }
  }
}

// ---------------- big-tile pipelined bf16 NT GEMM: 256x256 tile, BK=32, 4-deep LDS pipeline ----------------
// C[M,N] = A[M,K] * B[N,K]^T, bf16 out. Requires M%256==0, N%256==0, K%32==0, K>=128.
__global__ __launch_bounds__(512, 2) void gemm_bt_256(const bf16* __restrict__ A,
                                                      const bf16* __restrict__ Bm,
                                                      bf16* __restrict__ C,
                                                      int M, int N, int K) {
  __shared__ bf16 As[4][256][32];   // 4 x 16KB
  __shared__ bf16 Bs[4][256][32];   // 4 x 16KB
  const int tid  = threadIdx.x;
  const int lane = tid & 63;
  const int wave = tid >> 6;        // 0..7
  const int wm = wave >> 2;         // 0..1  (128-row half)
  const int wn = wave & 3;          // 0..3  (64-col quarter)
  const int fr = lane & 15;
  const int fq = lane >> 4;
  const int bm = blockIdx.y * 256;
  const int bn = blockIdx.x * 256;
  const int NT = K >> 5;            // K-tiles of 32

  // ---- staging setup: linear LDS dest, inverse-swizzled global source (rule 21) ----
  const int arow = tid >> 2;                      // 0..127
  const int slot = tid & 3;                       // 16B slot within 64B row
  const int scol = ((slot ^ (arow & 3)) << 3);    // swizzled source col (bf16)
  const bf16* gA0 = A  + (size_t)(bm + arow) * K + scol;
  const bf16* gA1 = A  + (size_t)(bm + 128 + arow) * K + scol;
  const bf16* gB0 = Bm + (size_t)(bn + arow) * K + scol;
  const bf16* gB1 = Bm + (size_t)(bn + 128 + arow) * K + scol;
  char* lA0 = (char*)As + arow * 64 + slot * 16;
  char* lB0 = (char*)Bs + arow * 64 + slot * 16;

#define STAGE256(kt) do {                                   \
    const int bi_ = (kt) & 3;                               \
    const size_t ko_ = (size_t)(kt) << 5;                   \
    gload_lds16(gA0 + ko_, lA0 + bi_ * 16384);              \
    gload_lds16(gA1 + ko_, lA0 + 8192 + bi_ * 16384);       \
    gload_lds16(gB0 + ko_, lB0 + bi_ * 16384);              \
    gload_lds16(gB1 + ko_, lB0 + 8192 + bi_ * 16384);       \
  } while (0)

  // ---- frag-read setup (swizzled k-slot) ----
  const int aoff = ((fq ^ (fr & 3)) << 4);        // swizzled 16B slot within row
  const char* rA = (char*)As + aoff + (wm * 128 + fr) * 64;
  const char* rB = (char*)Bs + aoff + (wn * 64 + fr) * 64;

  floatx4 acc[8][4];
  #pragma unroll
  for (int m = 0; m < 8; ++m)
    #pragma unroll
    for (int n = 0; n < 4; ++n)
      #pragma unroll
      for (int r = 0; r < 4; ++r) acc[m][n][r] = 0.f;

  // prologue: stage tiles 0,1,2; wait tile 0 (8 = tiles 1,2 may stay in flight)
  STAGE256(0);
  STAGE256(1);
  STAGE256(2);
  __builtin_amdgcn_sched_barrier(0);
  asm volatile("s_waitcnt vmcnt(8)" ::: "memory");
  __builtin_amdgcn_s_barrier();
  __builtin_amdgcn_sched_barrier(0);

  for (int kt = 0; kt < NT; ++kt) {
    const int bi = kt & 3;
    if (kt + 3 < NT) STAGE256(kt + 3);
    const char* pa = rA + bi * 16384;
    const char* pb = rB + bi * 16384;
    bf16x8 a8[8], b8[4];
    #pragma unroll
    for (int m = 0; m < 8; ++m) a8[m] = *(const bf16x8*)(pa + m * 1024);
    #pragma unroll
    for (int n = 0; n < 4; ++n) b8[n] = *(const bf16x8*)(pb + n * 1024);
    __builtin_amdgcn_s_setprio(1);
    #pragma unroll
    for (int m = 0; m < 8; ++m)
      #pragma unroll
      for (int n = 0; n < 4; ++n)
        acc[m][n] = __builtin_amdgcn_mfma_f32_16x16x32_bf16(a8[m], b8[n], acc[m][n], 0, 0, 0);
    __builtin_amdgcn_s_setprio(0);
    if (kt < NT - 1) {
      __builtin_amdgcn_sched_barrier(0);
      if (kt <= NT - 4)      { asm volatile("s_waitcnt vmcnt(8)" ::: "memory"); }
      else if (kt == NT - 3) { asm volatile("s_waitcnt vmcnt(4)" ::: "memory"); }
      else                   { asm volatile("s_waitcnt vmcnt(0)" ::: "memory"); }
      __builtin_amdgcn_s_barrier();
      __builtin_amdgcn_sched_barrier(0);
    }
  }
#undef STAGE256

  #pragma unroll
  for (int m = 0; m < 8; ++m) {
    const int row = bm + wm * 128 + (m << 4) + (fq << 2);
    #pragma unroll
    for (int n = 0; n < 4; ++n) {
      const int col = bn + wn * 64 + (n << 4) + fr;
      #pragma unroll
      for (int r = 0; r < 4; ++r)
        C[(size_t)(row + r) * N + col] = (bf16)acc[m][n][r];
    }
  }
}

// ---------------- bf16 NT GEMM (m97 structure): C[M,N] = A[M,K] * B[N,K]^T ----------------
template <typename OT>
__global__ __launch_bounds__(256) void gemm_bt(const bf16* __restrict__ A,
                                               const bf16* __restrict__ Bm,
                                               OT* __restrict__ C,
                                               int M, int N, int K) {
  __shared__ bf16 As[128 * 32];
  __shared__ bf16 Bs[128 * 32];
  const int tid  = threadIdx.x;
  const int lane = tid & 63;
  const int wave = tid >> 6;
  const int bm = blockIdx.y * 128;
  const int bn = blockIdx.x * 128;
  const int wr = (wave >> 1) << 6;
  const int wc = (wave & 1) << 6;
  const int fr = lane & 15;
  const int fq = lane >> 4;

  const int srow  = tid >> 2;         // 0..63
  const int skoff = (tid & 3) << 3;   // 0,8,16,24 (bf16 elems)
  const bf16* ga0 = A  + (size_t)(bm + srow) * K + skoff;
  const bf16* ga1 = A  + (size_t)(bm + 64 + srow) * K + skoff;
  const bf16* gb0 = Bm + (size_t)(bn + srow) * K + skoff;
  const bf16* gb1 = Bm + (size_t)(bn + 64 + srow) * K + skoff;
  char* la0 = (char*)As + (wave << 10);
  char* la1 = (char*)As + 4096 + (wave << 10);
  char* lb0 = (char*)Bs + (wave << 10);
  char* lb1 = (char*)Bs + 4096 + (wave << 10);

  floatx4 acc[4][4];
  #pragma unroll
  for (int i = 0; i < 4; ++i)
    #pragma unroll
    for (int j = 0; j < 4; ++j)
      #pragma unroll
      for (int r = 0; r < 4; ++r) acc[i][j][r] = 0.f;

  for (int k0 = 0; k0 < K; k0 += 32) {
    gload_lds16(ga0 + k0, la0);
    gload_lds16(ga1 + k0, la1);
    gload_lds16(gb0 + k0, lb0);
    gload_lds16(gb1 + k0, lb1);
    __syncthreads();
    bf16x8 af[4], bfr[4];
    #pragma unroll
    for (int i = 0; i < 4; ++i)
      af[i] = *(const bf16x8*)&As[(wr + (i << 4) + fr) * 32 + (fq << 3)];
    #pragma unroll
    for (int j = 0; j < 4; ++j)
      bfr[j] = *(const bf16x8*)&Bs[(wc + (j << 4) + fr) * 32 + (fq << 3)];
    #pragma unroll
    for (int i = 0; i < 4; ++i)
      #pragma unroll
      for (int j = 0; j < 4; ++j)
        acc[i][j] = __builtin_amdgcn_mfma_f32_16x16x32_bf16(af[i], bfr[j], acc[i][j], 0, 0, 0);
    __syncthreads();
  }
  #pragma unroll
  for (int i = 0; i < 4; ++i) {
    const int row = bm + wr + (i << 4) + (fq << 2);
    #pragma unroll
    for (int j = 0; j < 4; ++j) {
      const int col = bn + wc + (j << 4) + fr;
      #pragma unroll
      for (int r = 0; r < 4; ++r)
        C[(size_t)(row + r) * N + col] = (OT)acc[i][j][r];
    }
  }
}

// ---------------- split-K variant: block z computes K-slice [z*KS, (z+1)*KS), f32 partials ----------------
__global__ __launch_bounds__(256) void gemm_bt_sk(const bf16* __restrict__ A,
                                                  const bf16* __restrict__ Bm,
                                                  float* __restrict__ Cp,
                                                  int M, int N, int ldk, int KS) {
  __shared__ bf16 As[128 * 32];
  __shared__ bf16 Bs[128 * 32];
  const int tid  = threadIdx.x;
  const int lane = tid & 63;
  const int wave = tid >> 6;
  const int bm = blockIdx.y * 128;
  const int bn = blockIdx.x * 128;
  const int z  = blockIdx.z;
  const int wr = (wave >> 1) << 6;
  const int wc = (wave & 1) << 6;
  const int fr = lane & 15;
  const int fq = lane >> 4;

  const int srow  = tid >> 2;
  const int skoff = (tid & 3) << 3;
  const size_t kbase = (size_t)z * KS + skoff;
  const bf16* ga0 = A  + (size_t)(bm + srow) * ldk + kbase;
  const bf16* ga1 = A  + (size_t)(bm + 64 + srow) * ldk + kbase;
  const bf16* gb0 = Bm + (size_t)(bn + srow) * ldk + kbase;
  const bf16* gb1 = Bm + (size_t)(bn + 64 + srow) * ldk + kbase;
  char* la0 = (char*)As + (wave << 10);
  char* la1 = (char*)As + 4096 + (wave << 10);
  char* lb0 = (char*)Bs + (wave << 10);
  char* lb1 = (char*)Bs + 4096 + (wave << 10);

  floatx4 acc[4][4];
  #pragma unroll
  for (int i = 0; i < 4; ++i)
    #pragma unroll
    for (int j = 0; j < 4; ++j)
      #pragma unroll
      for (int r = 0; r < 4; ++r) acc[i][j][r] = 0.f;

  for (int k0 = 0; k0 < KS; k0 += 32) {
    gload_lds16(ga0 + k0, la0);
    gload_lds16(ga1 + k0, la1);
    gload_lds16(gb0 + k0, lb0);
    gload_lds16(gb1 + k0, lb1);
    __syncthreads();
    bf16x8 af[4], bfr[4];
    #pragma unroll
    for (int i = 0; i < 4; ++i)
      af[i] = *(const bf16x8*)&As[(wr + (i << 4) + fr) * 32 + (fq << 3)];
    #pragma unroll
    for (int j = 0; j < 4; ++j)
      bfr[j] = *(const bf16x8*)&Bs[(wc + (j << 4) + fr) * 32 + (fq << 3)];
    #pragma unroll
    for (int i = 0; i < 4; ++i)
      #pragma unroll
      for (int j = 0; j < 4; ++j)
        acc[i][j] = __builtin_amdgcn_mfma_f32_16x16x32_bf16(af[i], bfr[j], acc[i][j], 0, 0, 0);
    __syncthreads();
  }
  float* Cb = Cp + (size_t)z * M * N;
  #pragma unroll
  for (int i = 0; i < 4; ++i) {
    const int row = bm + wr + (i << 4) + (fq << 2);
    #pragma unroll
    for (int j = 0; j < 4; ++j) {
      const int col = bn + wc + (j << 4) + fr;
      #pragma unroll
      for (int r = 0; r < 4; ++r)
        Cb[(size_t)(row + r) * N + col] = acc[i][j][r];
    }
  }
}

// fixed-order split-K reduce -> f32 (deterministic)
template <int KS>
__global__ __launch_bounds__(256) void reduce_sk_k(const float* __restrict__ part,
                                                   float* __restrict__ out,
                                                   int n4, size_t mn) {
  const int i = blockIdx.x * 256 + threadIdx.x;
  if (i >= n4) return;
  const size_t e = (size_t)i * 4;
  floatx4 s = *(const floatx4*)&part[e];
  #pragma unroll
  for (int z = 1; z < KS; ++z) {
    floatx4 v = *(const floatx4*)&part[(size_t)z * mn + e];
    #pragma unroll
    for (int j = 0; j < 4; ++j) s[j] += v[j];
  }
  *(floatx4*)&out[e] = s;
}

// ---------------- depthwise causal conv(4) + bias + SiLU ----------------
__global__ __launch_bounds__(256) void conv_silu_k(const bf16* __restrict__ xr,
                                                   const float* __restrict__ cw,
                                                   const float* __restrict__ cb,
                                                   bf16* __restrict__ u_btd,
                                                   float* __restrict__ u_dtl) {
  __shared__ float tile[32][65];
  const int tid = threadIdx.x;
  const int d0 = blockIdx.x << 6;   // 64 channels per block
  const int t0 = blockIdx.y << 5;   // 32 timesteps per block
  const int b  = blockIdx.z;
  const int dl = tid & 63, tq = tid >> 6;
  const int d  = d0 + dl;
  const float w0 = cw[d * 4 + 0], w1 = cw[d * 4 + 1], w2 = cw[d * 4 + 2], w3 = cw[d * 4 + 3];
  const float bias = cb[d];
  #pragma unroll
  for (int i = 0; i < 8; ++i) {
    const int t = tq * 8 + i;       // 0..31
    const int tg = t0 + t;
    float acc = bias;
    {
      int tt = tg - 3;
      if (tt >= 0) acc += w0 * (float)xr[((size_t)b * SEQLEN + tt) * 4096 + d];
    }
    {
      int tt = tg - 2;
      if (tt >= 0) acc += w1 * (float)xr[((size_t)b * SEQLEN + tt) * 4096 + d];
    }
    {
      int tt = tg - 1;
      if (tt >= 0) acc += w2 * (float)xr[((size_t)b * SEQLEN + tt) * 4096 + d];
    }
    acc += w3 * (float)xr[((size_t)b * SEQLEN + tg) * 4096 + d];
    const float uval = siluf_(acc);
    u_btd[((size_t)b * SEQLEN + tg) * DINNER + d] = (bf16)uval;
    tile[t][dl] = uval;
  }
  __syncthreads();
  const int dr = tid >> 2;            // 0..63
  const int tcol = (tid & 3) << 3;    // 0,8,16,24
  float vals[8];
  #pragma unroll
  for (int i = 0; i < 8; ++i) vals[i] = tile[tcol + i][dr];
  #pragma unroll
  for (int i = 0; i < 8; ++i)
    u_dtl[((size_t)b * DINNER + d0 + dr) * SEQLEN + t0 + tcol + i] = vals[i];
}

// ---------------- dt projection + softplus + clamp, transposed output (b,d,t) ----------------
__global__ __launch_bounds__(256) void dtproj_k(const float* __restrict__ x_dbl,
                                                const float* __restrict__ w,
                                                const float* __restrict__ bias,
                                                float* __restrict__ dt_t) {
  __shared__ float r_s[64][65];
  __shared__ float w_s[64][65];
  const int tid  = threadIdx.x;
  const int d0   = blockIdx.x << 6;
  const int row0 = blockIdx.y << 6;
  #pragma unroll
  for (int j = 0; j < 4; ++j) {
    int id = tid + (j << 8);          // 0..1023
    int r  = id >> 4;
    int kq = (id & 15) << 2;
    floatx4 v = *(const floatx4*)&x_dbl[(size_t)(row0 + r) * NPROJ + kq];
    r_s[r][kq] = v[0]; r_s[r][kq + 1] = v[1]; r_s[r][kq + 2] = v[2]; r_s[r][kq + 3] = v[3];
    floatx4 ww = *(const floatx4*)&w[(size_t)(d0 + r) * 64 + kq];
    w_s[r][kq] = ww[0]; w_s[r][kq + 1] = ww[1]; w_s[r][kq + 2] = ww[2]; w_s[r][kq + 3] = ww[3];
  }
  __syncthreads();
  const int tl = tid & 15, dl = tid >> 4;
  float acc[4][4] = {};               // [t][d]
  #pragma unroll 8
  for (int k = 0; k < 64; ++k) {
    float a[4], bb[4];
    #pragma unroll
    for (int i = 0; i < 4; ++i) a[i] = r_s[tl * 4 + i][k];
    #pragma unroll
    for (int j = 0; j < 4; ++j) bb[j] = w_s[dl + (j << 4)][k];
    #pragma unroll
    for (int i = 0; i < 4; ++i)
      #pragma unroll
      for (int j = 0; j < 4; ++j) acc[i][j] += a[i] * bb[j];
  }
  const int bb_ = row0 >> 11;
  const int tbase = (row0 & 2047) + tl * 4;
  #pragma unroll
  for (int j = 0; j < 4; ++j) {
    const int dd = d0 + dl + (j << 4);
    const float bsv = bias[dd];
    floatx4 o;
    #pragma unroll
    for (int i = 0; i < 4; ++i) {
      float v = acc[i][j] + bsv;
      float sp = (v > 20.f) ? v : __logf(1.f + __expf(v));
      o[i] = fminf(sp, 10.f);
    }
    *(floatx4*)&dt_t[((size_t)bb_ * DINNER + dd) * SEQLEN + tbase] = o;
  }
}

// ---------------- chunked selective scan, registers-own-s layout ----------------
__global__ __launch_bounds__(256) void scanA_k(const float* __restrict__ dt_t,
                                               const float* __restrict__ u_dtl,
                                               const float* __restrict__ x_dbl,
                                               const float* __restrict__ A_log,
                                               float* __restrict__ hfin,
                                               float* __restrict__ Pbuf) {
  __shared__ float Bs_[TCC][16];
  const int tid = threadIdx.x;
  const int b = blockIdx.z, c = blockIdx.y;
  const int d = (blockIdx.x << 8) + tid;
  const int t0 = c * TCC;
  {
    const int t = tid >> 2, sq = (tid & 3) << 2;
    *(floatx4*)&Bs_[t][sq] = *(const floatx4*)&x_dbl[((size_t)b * SEQLEN + t0 + t) * NPROJ + 64 + sq];
  }
  float A_[DSTATE];
  #pragma unroll
  for (int q = 0; q < 4; ++q) {
    floatx4 al = *(const floatx4*)&A_log[d * DSTATE + q * 4];
    #pragma unroll
    for (int j = 0; j < 4; ++j) A_[q * 4 + j] = -__expf(al[j]);
  }
  __syncthreads();
  float h[DSTATE];
  #pragma unroll
  for (int s = 0; s < DSTATE; ++s) h[s] = 0.f;
  float sdt = 0.f;
  const float* dtp = dt_t + ((size_t)b * DINNER + d) * SEQLEN + t0;
  const float* up  = u_dtl + ((size_t)b * DINNER + d) * SEQLEN + t0;
  for (int tq = 0; tq < TCC; tq += 4) {
    floatx4 dt4 = *(const floatx4*)&dtp[tq];
    floatx4 u4  = *(const floatx4*)&up[tq];
    #pragma unroll
    for (int j = 0; j < 4; ++j) {
      const float dtv = dt4[j];
      const float xin = dtv * u4[j];
      sdt += dtv;
      floatx4 Brow[4];
      #pragma unroll
      for (int q = 0; q < 4; ++q) Brow[q] = *(const floatx4*)&Bs_[tq + j][q * 4];
      #pragma unroll
      for (int s = 0; s < DSTATE; ++s)
        h[s] = __expf(dtv * A_[s]) * h[s] + xin * Brow[s >> 2][s & 3];
    }
  }
  const size_t base = (((size_t)b * NCHUNK + c) * DINNER + d) * DSTATE;
  #pragma unroll
  for (int q = 0; q < 4; ++q) {
    floatx4 hv, pv;
    #pragma unroll
    for (int j = 0; j < 4; ++j) {
      hv[j] = h[q * 4 + j];
      pv[j] = __expf(A_[q * 4 + j] * sdt);
    }
    *(floatx4*)&hfin[base + q * 4] = hv;
    *(floatx4*)&Pbuf[base + q * 4] = pv;
  }
}

__global__ __launch_bounds__(256) void scanB_k(const float* __restrict__ hfin,
                                               const float* __restrict__ Pbuf,
                                               float* __restrict__ hin) {
  const int flat = blockIdx.x * 256 + threadIdx.x;   // 0..65535
  const int b  = flat >> 15;
  const int ds = flat & 32767;
  float h = 0.f;
  hin[((size_t)b * NCHUNK) * 32768 + ds] = 0.f;
  for (int c = 1; c < NCHUNK; ++c) {
    const size_t prev = ((size_t)b * NCHUNK + c - 1) * 32768 + ds;
    h = hfin[prev] + Pbuf[prev] * h;
    hin[((size_t)b * NCHUNK + c) * 32768 + ds] = h;
  }
}

__global__ __launch_bounds__(256) void scanC_k(const float* __restrict__ dt_t,
                                               const float* __restrict__ u_dtl,
                                               const float* __restrict__ x_dbl,
                                               const float* __restrict__ A_log,
                                               const float* __restrict__ Dp,
                                               const float* __restrict__ hin,
                                               const bf16* __restrict__ xr,
                                               bf16* __restrict__ yres) {
  __shared__ float Bs_[TCC][16];
  __shared__ float Cs_[TCC][16];
  const int tid = threadIdx.x;
  const int b = blockIdx.z, c = blockIdx.y;
  const int d = (blockIdx.x << 8) + tid;
  const int t0 = c * TCC;
  {
    const int t = tid >> 2, sq = (tid & 3) << 2;
    *(floatx4*)&Bs_[t][sq] = *(const floatx4*)&x_dbl[((size_t)b * SEQLEN + t0 + t) * NPROJ + 64 + sq];
    *(floatx4*)&Cs_[t][sq] = *(const floatx4*)&x_dbl[((size_t)b * SEQLEN + t0 + t) * NPROJ + 80 + sq];
  }
  float A_[DSTATE];
  #pragma unroll
  for (int q = 0; q < 4; ++q) {
    floatx4 al = *(const floatx4*)&A_log[d * DSTATE + q * 4];
    #pragma unroll
    for (int j = 0; j < 4; ++j) A_[q * 4 + j] = -__expf(al[j]);
  }
  float h[DSTATE];
  const size_t base = (((size_t)b * NCHUNK + c) * DINNER + d) * DSTATE;
  #pragma unroll
  for (int q = 0; q < 4; ++q) {
    floatx4 hv = *(const floatx4*)&hin[base + q * 4];
    #pragma unroll
    for (int j = 0; j < 4; ++j) h[q * 4 + j] = hv[j];
  }
  const float Dv = Dp[d];
  __syncthreads();
  const float* dtp = dt_t + ((size_t)b * DINNER + d) * SEQLEN + t0;
  const float* up  = u_dtl + ((size_t)b * DINNER + d) * SEQLEN + t0;
  const bf16* resp = xr + ((size_t)b * SEQLEN + t0) * 4096 + 2048 + d;
  bf16* yp = yres + ((size_t)b * SEQLEN + t0) * DINNER + d;
  for (int tq = 0; tq < TCC; tq += 4) {
    floatx4 dt4 = *(const floatx4*)&dtp[tq];
    floatx4 u4  = *(const floatx4*)&up[tq];
    #pragma unroll
    for (int j = 0; j < 4; ++j) {
      const int t = tq + j;
      const float dtv = dt4[j];
      const float uv  = u4[j];
      const float xin = dtv * uv;
      float acc = Dv * uv;
      floatx4 Brow[4], Crow[4];
      #pragma unroll
      for (int q = 0; q < 4; ++q) {
        Brow[q] = *(const floatx4*)&Bs_[t][q * 4];
        Crow[q] = *(const floatx4*)&Cs_[t][q * 4];
      }
      #pragma unroll
      for (int s = 0; s < DSTATE; ++s) {
        h[s] = __expf(dtv * A_[s]) * h[s] + xin * Brow[s >> 2][s & 3];
        acc += h[s] * Crow[s >> 2][s & 3];
      }
      const float r = (float)resp[(size_t)t * 4096];
      yp[(size_t)t * DINNER] = (bf16)(acc * siluf_(r));
    }
  }
}

extern "C" void kernel_launch(void* const* d_in, const int* in_sizes, int n_in,
                              void* d_out, int out_size, void* d_ws, size_t ws_size,
                              hipStream_t stream) {
  const float* x         = (const float*)d_in[0];
  const float* in_proj_w = (const float*)d_in[1];
  const float* conv_w    = (const float*)d_in[2];
  const float* conv_b    = (const float*)d_in[3];
  const float* x_proj_w  = (const float*)d_in[4];
  const float* dt_proj_w = (const float*)d_in[5];
  const float* dt_proj_b = (const float*)d_in[6];
  const float* A_log     = (const float*)d_in[7];
  const float* Dp        = (const float*)d_in[8];
  const float* out_proj_w= (const float*)d_in[9];
  float* out = (float*)d_out;

  char* ws = (char*)d_ws;
  size_t off = 0;
  auto alloc = [&](size_t bytes) -> void* {
    void* p = ws + off;
    off += (bytes + 255) & ~(size_t)255;
    return p;
  };
  // long-lived buffers first
  bf16*  wo_bf  = (bf16*) alloc((size_t)DMODEL * DINNER * 2);
  bf16*  xw_bf  = (bf16*) alloc((size_t)NPROJ * DINNER * 2);
  bf16*  yres   = (bf16*) alloc((size_t)NROWS * DINNER * 2);
  float* x_dbl  = (float*)alloc((size_t)NROWS * NPROJ * 4);
  float* dt_t   = (float*)alloc((size_t)BATCH * DINNER * SEQLEN * 4);
  float* u_dtl  = (float*)alloc((size_t)BATCH * DINNER * SEQLEN * 4);
  float* hfin   = (float*)alloc((size_t)BATCH * NCHUNK * DINNER * DSTATE * 4);
  float* Pbuf   = (float*)alloc((size_t)BATCH * NCHUNK * DINNER * DSTATE * 4);
  float* hin    = (float*)alloc((size_t)BATCH * NCHUNK * DINNER * DSTATE * 4);
  // overlay region: early-dead buffers, later reused for split-K partials
  const size_t mark = off;
  bf16*  x_bf   = (bf16*) alloc((size_t)NROWS * DMODEL * 2);      // dead after in_proj
  bf16*  wi_bf  = (bf16*) alloc((size_t)2 * DINNER * DMODEL * 2); // dead after in_proj
  bf16*  xr     = (bf16*) alloc((size_t)NROWS * 4096 * 2);        // dead after scanC
  bf16*  u_btd  = (bf16*) alloc((size_t)NROWS * DINNER * 2);      // dead after x_proj
  // xpart (16.8 MB) aliases x_bf+wi_bf (25.2 MB, dead by x_proj time)
  float* xpart  = (float*)(ws + mark);
  // opart (67 MB) aliases x_bf..u_btd (75.5 MB, all dead by out_proj time)
  float* opart  = (float*)(ws + mark);

  // fused casts (1 launch)
  cast_all_k<<<CAST_TOT4 / 256, 256, 0, stream>>>(x, in_proj_w, out_proj_w, x_proj_w,
                                                  x_bf, wi_bf, wo_bf, xw_bf);
  // in_proj: (4096 x 4096) = x_bf (4096x1024) @ wi_bf^T  -- big-tile pipelined kernel
  gemm_bt_256<<<dim3(4096 / 256, NROWS / 256), 512, 0, stream>>>(x_bf, wi_bf, xr, NROWS, 4096, DMODEL);
  // conv + SiLU
  conv_silu_k<<<dim3(DINNER / 64, SEQLEN / 32, BATCH), 256, 0, stream>>>(xr, conv_w, conv_b, u_btd, u_dtl);
  // x_proj: (4096 x 128) = u (4096x2048) @ xw^T, split-K x8
  gemm_bt_sk<<<dim3(1, 32, 8), 256, 0, stream>>>(u_btd, xw_bf, xpart, NROWS, NPROJ, DINNER, DINNER / 8);
  reduce_sk_k<8><<<(NROWS * NPROJ / 4 + 255) / 256, 256, 0, stream>>>(xpart, x_dbl, NROWS * NPROJ / 4, (size_t)NROWS * NPROJ);
  // dt proj + softplus + clamp -> (b,d,t)
  dtproj_k<<<dim3(DINNER / 64, NROWS / 64), 256, 0, stream>>>(x_dbl, dt_proj_w, dt_proj_b, dt_t);
  // chunked selective scan (registers-own-s)
  scanA_k<<<dim3(DINNER / 256, NCHUNK, BATCH), 256, 0, stream>>>(dt_t, u_dtl, x_dbl, A_log, hfin, Pbuf);
  scanB_k<<<dim3(BATCH * DINNER * DSTATE / 256), 256, 0, stream>>>(hfin, Pbuf, hin);
  scanC_k<<<dim3(DINNER / 256, NCHUNK, BATCH), 256, 0, stream>>>(dt_t, u_dtl, x_dbl, A_log, Dp, hin, xr, yres);
  // out_proj: (4096 x 1024) = yres (4096x2048) @ wo^T, split-K x4
  gemm_bt_sk<<<dim3(DMODEL / 128, NROWS / 128, 4), 256, 0, stream>>>(yres, wo_bf, opart, NROWS, DMODEL, DINNER, DINNER / 4);
  reduce_sk_k<4><<<(NROWS * DMODEL / 4 + 255) / 256, 256, 0, stream>>>(opart, out, NROWS * DMODEL / 4, (size_t)NROWS * DMODEL);
}

// Round 6
// 243.523 us; speedup vs baseline: 2.6890x; 1.0867x over previous
//
#include <hip/hip_runtime.h>
#include <hip/hip_bf16.h>
#include <stdint.h>

#define BATCH 2
#define SEQLEN 2048
#define DMODEL 1024
#define DINNER 2048
#define DSTATE 16
#define DTRANK 64
#define NPROJ 128            // 96 padded to 128 for the MFMA GEMM
#define NROWS (BATCH*SEQLEN) // 4096
#define NCHUNK 64
#define TCC 32               // timesteps per scan chunk
#define LOG2E 1.4426950408889634f

typedef __bf16 bf16;
typedef __bf16 bf16x8 __attribute__((ext_vector_type(8)));
typedef __bf16 bf16x4 __attribute__((ext_vector_type(4)));
typedef float  floatx4 __attribute__((ext_vector_type(4)));

#if __has_builtin(__builtin_amdgcn_exp2f)
#define EXP2F __builtin_amdgcn_exp2f
#else
#define EXP2F exp2f
#endif

__device__ __forceinline__ float sigmoidf_(float x) { return 1.f / (1.f + __expf(-x)); }
__device__ __forceinline__ float siluf_(float x)    { return x * sigmoidf_(x); }

__device__ __forceinline__ void gload_lds16(const void* gsrc, void* ldsdst) {
  auto g = (const __attribute__((address_space(1))) uint32_t*)(uintptr_t)gsrc;
  uint32_t lo = (uint32_t)(uintptr_t)ldsdst;
  auto l = (__attribute__((address_space(3))) uint32_t*)lo;
  __builtin_amdgcn_global_load_lds(g, l, 16, 0, 0);
}

// ---------------- fused casts ----------------
#define CAST_XN   (NROWS * DMODEL)
#define CAST_WIN  (2 * DINNER * DMODEL)
#define CAST_WON  (DMODEL * DINNER)
#define CAST_XWN  (NPROJ * DINNER)
#define CAST_TOT4 ((CAST_XN + CAST_WIN + CAST_WON + CAST_XWN) / 4)

__device__ __forceinline__ void cvt4(const float* in, bf16* out) {
  floatx4 v = *(const floatx4*)in;
  bf16x4 o;
  #pragma unroll
  for (int j = 0; j < 4; ++j) o[j] = (bf16)v[j];
  *(bf16x4*)out = o;
}

__global__ __launch_bounds__(256) void cast_all_k(const float* __restrict__ x,
                                                  const float* __restrict__ wi,
                                                  const float* __restrict__ wo,
                                                  const float* __restrict__ xw,
                                                  bf16* __restrict__ x_bf,
                                                  bf16* __restrict__ wi_bf,
                                                  bf16* __restrict__ wo_bf,
                                                  bf16* __restrict__ xw_bf) {
  const int i = blockIdx.x * 256 + threadIdx.x;
  const int e = i * 4;
  if (e < CAST_XN) {
    cvt4(x + e, x_bf + e);
  } else if (e < CAST_XN + CAST_WIN) {
    const int o = e - CAST_XN;
    cvt4(wi + o, wi_bf + o);
  } else if (e < CAST_XN + CAST_WIN + CAST_WON) {
    const int o = e - CAST_XN - CAST_WIN;
    cvt4(wo + o, wo_bf + o);
  } else {
    const int o = e - CAST_XN - CAST_WIN - CAST_WON;
    const int row = o >> 11;
    bf16x4 z;
    if (row < 96) {
      cvt4(xw + o, xw_bf + o);
    } else {
      #pragma unroll
      for (int j = 0; j < 4; ++j) z[j] = (bf16)0.f;
      *(bf16x4*)&xw_bf[o] = z;
    }
  }
}

// ---------------- big-tile pipelined bf16 NT GEMM: 256x256 tile, BK=32, 4-deep LDS pipeline ----------------
__global__ __launch_bounds__(512, 2) void gemm_bt_256(const bf16* __restrict__ A,
                                                      const bf16* __restrict__ Bm,
                                                      bf16* __restrict__ C,
                                                      int M, int N, int K) {
  __shared__ bf16 As[4][256][32];
  __shared__ bf16 Bs[4][256][32];
  const int tid  = threadIdx.x;
  const int lane = tid & 63;
  const int wave = tid >> 6;
  const int wm = wave >> 2;
  const int wn = wave & 3;
  const int fr = lane & 15;
  const int fq = lane >> 4;
  const int bm = blockIdx.y * 256;
  const int bn = blockIdx.x * 256;
  const int NT = K >> 5;

  const int arow = tid >> 2;
  const int slot = tid & 3;
  const int scol = ((slot ^ (arow & 3)) << 3);
  const bf16* gA0 = A  + (size_t)(bm + arow) * K + scol;
  const bf16* gA1 = A  + (size_t)(bm + 128 + arow) * K + scol;
  const bf16* gB0 = Bm + (size_t)(bn + arow) * K + scol;
  const bf16* gB1 = Bm + (size_t)(bn + 128 + arow) * K + scol;
  char* lA0 = (char*)As + arow * 64 + slot * 16;
  char* lB0 = (char*)Bs + arow * 64 + slot * 16;

#define STAGE256(kt) do {                                   \
    const int bi_ = (kt) & 3;                               \
    const size_t ko_ = (size_t)(kt) << 5;                   \
    gload_lds16(gA0 + ko_, lA0 + bi_ * 16384);              \
    gload_lds16(gA1 + ko_, lA0 + 8192 + bi_ * 16384);       \
    gload_lds16(gB0 + ko_, lB0 + bi_ * 16384);              \
    gload_lds16(gB1 + ko_, lB0 + 8192 + bi_ * 16384);       \
  } while (0)

  const int aoff = ((fq ^ (fr & 3)) << 4);
  const char* rA = (char*)As + aoff + (wm * 128 + fr) * 64;
  const char* rB = (char*)Bs + aoff + (wn * 64 + fr) * 64;

  floatx4 acc[8][4];
  #pragma unroll
  for (int m = 0; m < 8; ++m)
    #pragma unroll
    for (int n = 0; n < 4; ++n)
      #pragma unroll
      for (int r = 0; r < 4; ++r) acc[m][n][r] = 0.f;

  STAGE256(0);
  STAGE256(1);
  STAGE256(2);
  __builtin_amdgcn_sched_barrier(0);
  asm volatile("s_waitcnt vmcnt(8)" ::: "memory");
  __builtin_amdgcn_s_barrier();
  __builtin_amdgcn_sched_barrier(0);

  for (int kt = 0; kt < NT; ++kt) {
    const int bi = kt & 3;
    if (kt + 3 < NT) STAGE256(kt + 3);
    const char* pa = rA + bi * 16384;
    const char* pb = rB + bi * 16384;
    bf16x8 a8[8], b8[4];
    #pragma unroll
    for (int m = 0; m < 8; ++m) a8[m] = *(const bf16x8*)(pa + m * 1024);
    #pragma unroll
    for (int n = 0; n < 4; ++n) b8[n] = *(const bf16x8*)(pb + n * 1024);
    __builtin_amdgcn_s_setprio(1);
    #pragma unroll
    for (int m = 0; m < 8; ++m)
      #pragma unroll
      for (int n = 0; n < 4; ++n)
        acc[m][n] = __builtin_amdgcn_mfma_f32_16x16x32_bf16(a8[m], b8[n], acc[m][n], 0, 0, 0);
    __builtin_amdgcn_s_setprio(0);
    if (kt < NT - 1) {
      __builtin_amdgcn_sched_barrier(0);
      if (kt <= NT - 4)      { asm volatile("s_waitcnt vmcnt(8)" ::: "memory"); }
      else if (kt == NT - 3) { asm volatile("s_waitcnt vmcnt(4)" ::: "memory"); }
      else                   { asm volatile("s_waitcnt vmcnt(0)" ::: "memory"); }
      __builtin_amdgcn_s_barrier();
      __builtin_amdgcn_sched_barrier(0);
    }
  }
#undef STAGE256

  #pragma unroll
  for (int m = 0; m < 8; ++m) {
    const int row = bm + wm * 128 + (m << 4) + (fq << 2);
    #pragma unroll
    for (int n = 0; n < 4; ++n) {
      const int col = bn + wn * 64 + (n << 4) + fr;
      #pragma unroll
      for (int r = 0; r < 4; ++r)
        C[(size_t)(row + r) * N + col] = (bf16)acc[m][n][r];
    }
  }
}

// ---------------- split-K GEMM: block z computes K-slice, f32 partials ----------------
__global__ __launch_bounds__(256) void gemm_bt_sk(const bf16* __restrict__ A,
                                                  const bf16* __restrict__ Bm,
                                                  float* __restrict__ Cp,
                                                  int M, int N, int ldk, int KS) {
  __shared__ bf16 As[128 * 32];
  __shared__ bf16 Bs[128 * 32];
  const int tid  = threadIdx.x;
  const int lane = tid & 63;
  const int wave = tid >> 6;
  const int bm = blockIdx.y * 128;
  const int bn = blockIdx.x * 128;
  const int z  = blockIdx.z;
  const int wr = (wave >> 1) << 6;
  const int wc = (wave & 1) << 6;
  const int fr = lane & 15;
  const int fq = lane >> 4;

  const int srow  = tid >> 2;
  const int skoff = (tid & 3) << 3;
  const size_t kbase = (size_t)z * KS + skoff;
  const bf16* ga0 = A  + (size_t)(bm + srow) * ldk + kbase;
  const bf16* ga1 = A  + (size_t)(bm + 64 + srow) * ldk + kbase;
  const bf16* gb0 = Bm + (size_t)(bn + srow) * ldk + kbase;
  const bf16* gb1 = Bm + (size_t)(bn + 64 + srow) * ldk + kbase;
  char* la0 = (char*)As + (wave << 10);
  char* la1 = (char*)As + 4096 + (wave << 10);
  char* lb0 = (char*)Bs + (wave << 10);
  char* lb1 = (char*)Bs + 4096 + (wave << 10);

  floatx4 acc[4][4];
  #pragma unroll
  for (int i = 0; i < 4; ++i)
    #pragma unroll
    for (int j = 0; j < 4; ++j)
      #pragma unroll
      for (int r = 0; r < 4; ++r) acc[i][j][r] = 0.f;

  for (int k0 = 0; k0 < KS; k0 += 32) {
    gload_lds16(ga0 + k0, la0);
    gload_lds16(ga1 + k0, la1);
    gload_lds16(gb0 + k0, lb0);
    gload_lds16(gb1 + k0, lb1);
    __syncthreads();
    bf16x8 af[4], bfr[4];
    #pragma unroll
    for (int i = 0; i < 4; ++i)
      af[i] = *(const bf16x8*)&As[(wr + (i << 4) + fr) * 32 + (fq << 3)];
    #pragma unroll
    for (int j = 0; j < 4; ++j)
      bfr[j] = *(const bf16x8*)&Bs[(wc + (j << 4) + fr) * 32 + (fq << 3)];
    #pragma unroll
    for (int i = 0; i < 4; ++i)
      #pragma unroll
      for (int j = 0; j < 4; ++j)
        acc[i][j] = __builtin_amdgcn_mfma_f32_16x16x32_bf16(af[i], bfr[j], acc[i][j], 0, 0, 0);
    __syncthreads();
  }
  float* Cb = Cp + (size_t)z * M * N;
  #pragma unroll
  for (int i = 0; i < 4; ++i) {
    const int row = bm + wr + (i << 4) + (fq << 2);
    #pragma unroll
    for (int j = 0; j < 4; ++j) {
      const int col = bn + wc + (j << 4) + fr;
      #pragma unroll
      for (int r = 0; r < 4; ++r)
        Cb[(size_t)(row + r) * N + col] = acc[i][j][r];
    }
  }
}

template <int KS>
__global__ __launch_bounds__(256) void reduce_sk_k(const float* __restrict__ part,
                                                   float* __restrict__ out,
                                                   int n4, size_t mn) {
  const int i = blockIdx.x * 256 + threadIdx.x;
  if (i >= n4) return;
  const size_t e = (size_t)i * 4;
  floatx4 s = *(const floatx4*)&part[e];
  #pragma unroll
  for (int z = 1; z < KS; ++z) {
    floatx4 v = *(const floatx4*)&part[(size_t)z * mn + e];
    #pragma unroll
    for (int j = 0; j < 4; ++j) s[j] += v[j];
  }
  *(floatx4*)&out[e] = s;
}

// ---------------- depthwise causal conv(4) + bias + SiLU; u_dtl now bf16 ----------------
__global__ __launch_bounds__(256) void conv_silu_k(const bf16* __restrict__ xr,
                                                   const float* __restrict__ cw,
                                                   const float* __restrict__ cb,
                                                   bf16* __restrict__ u_btd,
                                                   bf16* __restrict__ u_dtl) {
  __shared__ float tile[32][65];
  const int tid = threadIdx.x;
  const int d0 = blockIdx.x << 6;
  const int t0 = blockIdx.y << 5;
  const int b  = blockIdx.z;
  const int dl = tid & 63, tq = tid >> 6;
  const int d  = d0 + dl;
  const float w0 = cw[d * 4 + 0], w1 = cw[d * 4 + 1], w2 = cw[d * 4 + 2], w3 = cw[d * 4 + 3];
  const float bias = cb[d];
  #pragma unroll
  for (int i = 0; i < 8; ++i) {
    const int t = tq * 8 + i;
    const int tg = t0 + t;
    float acc = bias;
    {
      int tt = tg - 3;
      if (tt >= 0) acc += w0 * (float)xr[((size_t)b * SEQLEN + tt) * 4096 + d];
    }
    {
      int tt = tg - 2;
      if (tt >= 0) acc += w1 * (float)xr[((size_t)b * SEQLEN + tt) * 4096 + d];
    }
    {
      int tt = tg - 1;
      if (tt >= 0) acc += w2 * (float)xr[((size_t)b * SEQLEN + tt) * 4096 + d];
    }
    acc += w3 * (float)xr[((size_t)b * SEQLEN + tg) * 4096 + d];
    const float uval = siluf_(acc);
    u_btd[((size_t)b * SEQLEN + tg) * DINNER + d] = (bf16)uval;
    tile[t][dl] = uval;
  }
  __syncthreads();
  const int dr = tid >> 2;
  const int tcol = (tid & 3) << 3;
  bf16x8 ov;
  #pragma unroll
  for (int i = 0; i < 8; ++i) ov[i] = (bf16)tile[tcol + i][dr];
  *(bf16x8*)&u_dtl[((size_t)b * DINNER + d0 + dr) * SEQLEN + t0 + tcol] = ov;
}

// ---------------- dt projection + softplus + clamp -> bf16 (b,d,t) ----------------
__global__ __launch_bounds__(256) void dtproj_k(const float* __restrict__ x_dbl,
                                                const float* __restrict__ w,
                                                const float* __restrict__ bias,
                                                bf16* __restrict__ dt_t) {
  __shared__ float r_s[64][65];
  __shared__ float w_s[64][65];
  const int tid  = threadIdx.x;
  const int d0   = blockIdx.x << 6;
  const int row0 = blockIdx.y << 6;
  #pragma unroll
  for (int j = 0; j < 4; ++j) {
    int id = tid + (j << 8);
    int r  = id >> 4;
    int kq = (id & 15) << 2;
    floatx4 v = *(const floatx4*)&x_dbl[(size_t)(row0 + r) * NPROJ + kq];
    r_s[r][kq] = v[0]; r_s[r][kq + 1] = v[1]; r_s[r][kq + 2] = v[2]; r_s[r][kq + 3] = v[3];
    floatx4 ww = *(const floatx4*)&w[(size_t)(d0 + r) * 64 + kq];
    w_s[r][kq] = ww[0]; w_s[r][kq + 1] = ww[1]; w_s[r][kq + 2] = ww[2]; w_s[r][kq + 3] = ww[3];
  }
  __syncthreads();
  const int tl = tid & 15, dl = tid >> 4;
  float acc[4][4] = {};
  #pragma unroll 8
  for (int k = 0; k < 64; ++k) {
    float a[4], bb[4];
    #pragma unroll
    for (int i = 0; i < 4; ++i) a[i] = r_s[tl * 4 + i][k];
    #pragma unroll
    for (int j = 0; j < 4; ++j) bb[j] = w_s[dl + (j << 4)][k];
    #pragma unroll
    for (int i = 0; i < 4; ++i)
      #pragma unroll
      for (int j = 0; j < 4; ++j) acc[i][j] += a[i] * bb[j];
  }
  const int bb_ = row0 >> 11;
  const int tbase = (row0 & 2047) + tl * 4;
  #pragma unroll
  for (int j = 0; j < 4; ++j) {
    const int dd = d0 + dl + (j << 4);
    const float bsv = bias[dd];
    bf16x4 o;
    #pragma unroll
    for (int i = 0; i < 4; ++i) {
      float v = acc[i][j] + bsv;
      float sp = (v > 20.f) ? v : __logf(1.f + __expf(v));
      o[i] = (bf16)fminf(sp, 10.f);
    }
    *(bf16x4*)&dt_t[((size_t)bb_ * DINNER + dd) * SEQLEN + tbase] = o;
  }
}

// ---------------- chunked selective scan, registers-own-s, bf16 dt/u ----------------
__global__ __launch_bounds__(256) void scanA_k(const bf16* __restrict__ dt_t,
                                               const bf16* __restrict__ u_dtl,
                                               const float* __restrict__ x_dbl,
                                               const float* __restrict__ A_log,
                                               float* __restrict__ hfin,
                                               float* __restrict__ Pbuf) {
  __shared__ float Bs_[TCC][16];
  const int tid = threadIdx.x;
  const int b = blockIdx.z, c = blockIdx.y;
  const int d = (blockIdx.x << 8) + tid;
  const int t0 = c * TCC;
  if (tid < TCC * 4) {
    const int t = tid >> 2, sq = (tid & 3) << 2;
    *(floatx4*)&Bs_[t][sq] = *(const floatx4*)&x_dbl[((size_t)b * SEQLEN + t0 + t) * NPROJ + 64 + sq];
  }
  float Ae[DSTATE];
  #pragma unroll
  for (int q = 0; q < 4; ++q) {
    floatx4 al = *(const floatx4*)&A_log[d * DSTATE + q * 4];
    #pragma unroll
    for (int j = 0; j < 4; ++j) Ae[q * 4 + j] = -__expf(al[j]) * LOG2E;
  }
  __syncthreads();
  float h[DSTATE];
  #pragma unroll
  for (int s = 0; s < DSTATE; ++s) h[s] = 0.f;
  float sdt = 0.f;
  const bf16* dtp = dt_t + ((size_t)b * DINNER + d) * SEQLEN + t0;
  const bf16* up  = u_dtl + ((size_t)b * DINNER + d) * SEQLEN + t0;
  for (int tq = 0; tq < TCC; tq += 8) {
    bf16x8 dt8 = *(const bf16x8*)&dtp[tq];
    bf16x8 u8  = *(const bf16x8*)&up[tq];
    #pragma unroll
    for (int j = 0; j < 8; ++j) {
      const float dtv = (float)dt8[j];
      const float xin = dtv * (float)u8[j];
      sdt += dtv;
      floatx4 Brow[4];
      #pragma unroll
      for (int q = 0; q < 4; ++q) Brow[q] = *(const floatx4*)&Bs_[tq + j][q * 4];
      #pragma unroll
      for (int s = 0; s < DSTATE; ++s)
        h[s] = EXP2F(dtv * Ae[s]) * h[s] + xin * Brow[s >> 2][s & 3];
    }
  }
  const size_t base = (((size_t)b * NCHUNK + c) * DINNER + d) * DSTATE;
  #pragma unroll
  for (int q = 0; q < 4; ++q) {
    floatx4 hv, pv;
    #pragma unroll
    for (int j = 0; j < 4; ++j) {
      hv[j] = h[q * 4 + j];
      pv[j] = EXP2F(Ae[q * 4 + j] * sdt);
    }
    *(floatx4*)&hfin[base + q * 4] = hv;
    *(floatx4*)&Pbuf[base + q * 4] = pv;
  }
}

__global__ __launch_bounds__(256) void scanB_k(const float* __restrict__ hfin,
                                               const float* __restrict__ Pbuf,
                                               float* __restrict__ hin) {
  const int flat = blockIdx.x * 256 + threadIdx.x;
  const int b  = flat >> 15;
  const int ds = flat & 32767;
  float h = 0.f;
  hin[((size_t)b * NCHUNK) * 32768 + ds] = 0.f;
  for (int c = 1; c < NCHUNK; ++c) {
    const size_t prev = ((size_t)(b * NCHUNK + c - 1)) * 32768 + ds;
    h = hfin[prev] + Pbuf[prev] * h;
    hin[((size_t)(b * NCHUNK + c)) * 32768 + ds] = h;
  }
}

__global__ __launch_bounds__(256) void scanC_k(const bf16* __restrict__ dt_t,
                                               const bf16* __restrict__ u_dtl,
                                               const float* __restrict__ x_dbl,
                                               const float* __restrict__ A_log,
                                               const float* __restrict__ Dp,
                                               const float* __restrict__ hin,
                                               const bf16* __restrict__ xr,
                                               bf16* __restrict__ yres) {
  __shared__ float Bs_[TCC][16];
  __shared__ float Cs_[TCC][16];
  const int tid = threadIdx.x;
  const int b = blockIdx.z, c = blockIdx.y;
  const int d = (blockIdx.x << 8) + tid;
  const int t0 = c * TCC;
  if (tid < TCC * 4) {
    const int t = tid >> 2, sq = (tid & 3) << 2;
    *(floatx4*)&Bs_[t][sq] = *(const floatx4*)&x_dbl[((size_t)b * SEQLEN + t0 + t) * NPROJ + 64 + sq];
    *(floatx4*)&Cs_[t][sq] = *(const floatx4*)&x_dbl[((size_t)b * SEQLEN + t0 + t) * NPROJ + 80 + sq];
  }
  float Ae[DSTATE];
  #pragma unroll
  for (int q = 0; q < 4; ++q) {
    floatx4 al = *(const floatx4*)&A_log[d * DSTATE + q * 4];
    #pragma unroll
    for (int j = 0; j < 4; ++j) Ae[q * 4 + j] = -__expf(al[j]) * LOG2E;
  }
  float h[DSTATE];
  const size_t base = (((size_t)b * NCHUNK + c) * DINNER + d) * DSTATE;
  #pragma unroll
  for (int q = 0; q < 4; ++q) {
    floatx4 hv = *(const floatx4*)&hin[base + q * 4];
    #pragma unroll
    for (int j = 0; j < 4; ++j) h[q * 4 + j] = hv[j];
  }
  const float Dv = Dp[d];
  __syncthreads();
  const bf16* dtp = dt_t + ((size_t)b * DINNER + d) * SEQLEN + t0;
  const bf16* up  = u_dtl + ((size_t)b * DINNER + d) * SEQLEN + t0;
  const bf16* resp = xr + ((size_t)b * SEQLEN + t0) * 4096 + 2048 + d;
  bf16* yp = yres + ((size_t)b * SEQLEN + t0) * DINNER + d;
  for (int tq = 0; tq < TCC; tq += 8) {
    bf16x8 dt8 = *(const bf16x8*)&dtp[tq];
    bf16x8 u8  = *(const bf16x8*)&up[tq];
    #pragma unroll
    for (int j = 0; j < 8; ++j) {
      const int t = tq + j;
      const float dtv = (float)dt8[j];
      const float uv  = (float)u8[j];
      const float xin = dtv * uv;
      floatx4 Brow[4], Crow[4];
      #pragma unroll
      for (int q = 0; q < 4; ++q) {
        Brow[q] = *(const floatx4*)&Bs_[t][q * 4];
        Crow[q] = *(const floatx4*)&Cs_[t][q * 4];
      }
      float a4[4];
      #pragma unroll
      for (int q = 0; q < 4; ++q) a4[q] = 0.f;
      #pragma unroll
      for (int s = 0; s < DSTATE; ++s) {
        h[s] = EXP2F(dtv * Ae[s]) * h[s] + xin * Brow[s >> 2][s & 3];
        a4[s & 3] += h[s] * Crow[s >> 2][s & 3];
      }
      const float acc = ((a4[0] + a4[1]) + (a4[2] + a4[3])) + Dv * uv;
      const float r = (float)resp[(size_t)t * 4096];
      yp[(size_t)t * DINNER] = (bf16)(acc * siluf_(r));
    }
  }
}

extern "C" void kernel_launch(void* const* d_in, const int* in_sizes, int n_in,
                              void* d_out, int out_size, void* d_ws, size_t ws_size,
                              hipStream_t stream) {
  const float* x         = (const float*)d_in[0];
  const float* in_proj_w = (const float*)d_in[1];
  const float* conv_w    = (const float*)d_in[2];
  const float* conv_b    = (const float*)d_in[3];
  const float* x_proj_w  = (const float*)d_in[4];
  const float* dt_proj_w = (const float*)d_in[5];
  const float* dt_proj_b = (const float*)d_in[6];
  const float* A_log     = (const float*)d_in[7];
  const float* Dp        = (const float*)d_in[8];
  const float* out_proj_w= (const float*)d_in[9];
  float* out = (float*)d_out;

  char* ws = (char*)d_ws;
  size_t off = 0;
  auto alloc = [&](size_t bytes) -> void* {
    void* p = ws + off;
    off += (bytes + 255) & ~(size_t)255;
    return p;
  };
  // long-lived buffers first
  bf16*  wo_bf  = (bf16*) alloc((size_t)DMODEL * DINNER * 2);
  bf16*  xw_bf  = (bf16*) alloc((size_t)NPROJ * DINNER * 2);
  bf16*  yres   = (bf16*) alloc((size_t)NROWS * DINNER * 2);
  float* x_dbl  = (float*)alloc((size_t)NROWS * NPROJ * 4);
  bf16*  dt_t   = (bf16*) alloc((size_t)BATCH * DINNER * SEQLEN * 2);
  bf16*  u_dtl  = (bf16*) alloc((size_t)BATCH * DINNER * SEQLEN * 2);
  float* hfin   = (float*)alloc((size_t)BATCH * NCHUNK * DINNER * DSTATE * 4);
  float* Pbuf   = (float*)alloc((size_t)BATCH * NCHUNK * DINNER * DSTATE * 4);
  float* hin    = (float*)alloc((size_t)BATCH * NCHUNK * DINNER * DSTATE * 4);
  // overlay region: early-dead buffers, later reused for split-K partials
  const size_t mark = off;
  bf16*  x_bf   = (bf16*) alloc((size_t)NROWS * DMODEL * 2);      // dead after in_proj
  bf16*  wi_bf  = (bf16*) alloc((size_t)2 * DINNER * DMODEL * 2); // dead after in_proj
  bf16*  xr     = (bf16*) alloc((size_t)NROWS * 4096 * 2);        // dead after scanC
  bf16*  u_btd  = (bf16*) alloc((size_t)NROWS * DINNER * 2);      // dead after x_proj
  float* xpart  = (float*)(ws + mark);   // aliases x_bf+wi_bf (dead by x_proj)
  float* opart  = (float*)(ws + mark);   // aliases all 4 (dead by out_proj)

  cast_all_k<<<CAST_TOT4 / 256, 256, 0, stream>>>(x, in_proj_w, out_proj_w, x_proj_w,
                                                  x_bf, wi_bf, wo_bf, xw_bf);
  // in_proj
  gemm_bt_256<<<dim3(4096 / 256, NROWS / 256), 512, 0, stream>>>(x_bf, wi_bf, xr, NROWS, 4096, DMODEL);
  // conv + SiLU
  conv_silu_k<<<dim3(DINNER / 64, SEQLEN / 32, BATCH), 256, 0, stream>>>(xr, conv_w, conv_b, u_btd, u_dtl);
  // x_proj split-K x8
  gemm_bt_sk<<<dim3(1, 32, 8), 256, 0, stream>>>(u_btd, xw_bf, xpart, NROWS, NPROJ, DINNER, DINNER / 8);
  reduce_sk_k<8><<<(NROWS * NPROJ / 4 + 255) / 256, 256, 0, stream>>>(xpart, x_dbl, NROWS * NPROJ / 4, (size_t)NROWS * NPROJ);
  // dt proj
  dtproj_k<<<dim3(DINNER / 64, NROWS / 64), 256, 0, stream>>>(x_dbl, dt_proj_w, dt_proj_b, dt_t);
  // chunked selective scan
  scanA_k<<<dim3(DINNER / 256, NCHUNK, BATCH), 256, 0, stream>>>(dt_t, u_dtl, x_dbl, A_log, hfin, Pbuf);
  scanB_k<<<dim3(BATCH * DINNER * DSTATE / 256), 256, 0, stream>>>(hfin, Pbuf, hin);
  scanC_k<<<dim3(DINNER / 256, NCHUNK, BATCH), 256, 0, stream>>>(dt_t, u_dtl, x_dbl, A_log, Dp, hin, xr, yres);
  // out_proj split-K x4
  gemm_bt_sk<<<dim3(DMODEL / 128, NROWS / 128, 4), 256, 0, stream>>>(yres, wo_bf, opart, NROWS, DMODEL, DINNER, DINNER / 4);
  reduce_sk_k<4><<<(NROWS * DMODEL / 4 + 255) / 256, 256, 0, stream>>>(opart, out, NROWS * DMODEL / 4, (size_t)NROWS * DMODEL);
}

// Round 7
// 242.205 us; speedup vs baseline: 2.7037x; 1.0054x over previous
//
#include <hip/hip_runtime.h>
#include <hip/hip_bf16.h>
#include <stdint.h>

#define BATCH 2
#define SEQLEN 2048
#define DMODEL 1024
#define DINNER 2048
#define DSTATE 16
#define DTRANK 64
#define NPROJ 128            // 96 padded to 128 for the MFMA GEMM
#define NROWS (BATCH*SEQLEN) // 4096
#define NCHUNK 64
#define TCC 32               // timesteps per scan chunk
#define LOG2E 1.4426950408889634f

typedef __bf16 bf16;
typedef __bf16 bf16x8 __attribute__((ext_vector_type(8)));
typedef __bf16 bf16x4 __attribute__((ext_vector_type(4)));
typedef float  floatx4 __attribute__((ext_vector_type(4)));

#if __has_builtin(__builtin_amdgcn_exp2f)
#define EXP2F __builtin_amdgcn_exp2f
#else
#define EXP2F exp2f
#endif

__device__ __forceinline__ float sigmoidf_(float x) { return 1.f / (1.f + __expf(-x)); }
__device__ __forceinline__ float siluf_(float x)    { return x * sigmoidf_(x); }

__device__ __forceinline__ void gload_lds16(const void* gsrc, void* ldsdst) {
  auto g = (const __attribute__((address_space(1))) uint32_t*)(uintptr_t)gsrc;
  uint32_t lo = (uint32_t)(uintptr_t)ldsdst;
  auto l = (__attribute__((address_space(3))) uint32_t*)lo;
  __builtin_amdgcn_global_load_lds(g, l, 16, 0, 0);
}

// ---------------- fused casts ----------------
#define CAST_XN   (NROWS * DMODEL)
#define CAST_WIN  (2 * DINNER * DMODEL)
#define CAST_WON  (DMODEL * DINNER)
#define CAST_XWN  (NPROJ * DINNER)
#define CAST_TOT4 ((CAST_XN + CAST_WIN + CAST_WON + CAST_XWN) / 4)

__device__ __forceinline__ void cvt4(const float* in, bf16* out) {
  floatx4 v = *(const floatx4*)in;
  bf16x4 o;
  #pragma unroll
  for (int j = 0; j < 4; ++j) o[j] = (bf16)v[j];
  *(bf16x4*)out = o;
}

__global__ __launch_bounds__(256) void cast_all_k(const float* __restrict__ x,
                                                  const float* __restrict__ wi,
                                                  const float* __restrict__ wo,
                                                  const float* __restrict__ xw,
                                                  bf16* __restrict__ x_bf,
                                                  bf16* __restrict__ wi_bf,
                                                  bf16* __restrict__ wo_bf,
                                                  bf16* __restrict__ xw_bf) {
  const int i = blockIdx.x * 256 + threadIdx.x;
  const int e = i * 4;
  if (e < CAST_XN) {
    cvt4(x + e, x_bf + e);
  } else if (e < CAST_XN + CAST_WIN) {
    const int o = e - CAST_XN;
    cvt4(wi + o, wi_bf + o);
  } else if (e < CAST_XN + CAST_WIN + CAST_WON) {
    const int o = e - CAST_XN - CAST_WIN;
    cvt4(wo + o, wo_bf + o);
  } else {
    const int o = e - CAST_XN - CAST_WIN - CAST_WON;
    const int row = o >> 11;
    bf16x4 z;
    if (row < 96) {
      cvt4(xw + o, xw_bf + o);
    } else {
      #pragma unroll
      for (int j = 0; j < 4; ++j) z[j] = (bf16)0.f;
      *(bf16x4*)&xw_bf[o] = z;
    }
  }
}

// ---------------- big-tile pipelined bf16 NT GEMM: 256x256 tile, BK=32, 4-deep LDS pipeline ----------------
// LDS swizzle: f(row) = (row&3)^((row>>2)&3) applied to the 16B k-slot, both stage-source and read.
__global__ __launch_bounds__(512, 2) void gemm_bt_256(const bf16* __restrict__ A,
                                                      const bf16* __restrict__ Bm,
                                                      bf16* __restrict__ C,
                                                      int M, int N, int K) {
  __shared__ bf16 As[4][256][32];
  __shared__ bf16 Bs[4][256][32];
  const int tid  = threadIdx.x;
  const int lane = tid & 63;
  const int wave = tid >> 6;
  const int wm = wave >> 2;
  const int wn = wave & 3;
  const int fr = lane & 15;
  const int fq = lane >> 4;
  const int bm = blockIdx.y * 256;
  const int bn = blockIdx.x * 256;
  const int NT = K >> 5;

  const int arow = tid >> 2;
  const int slot = tid & 3;
  const int scol = ((slot ^ (arow & 3) ^ ((arow >> 2) & 3)) << 3);
  const bf16* gA0 = A  + (size_t)(bm + arow) * K + scol;
  const bf16* gA1 = A  + (size_t)(bm + 128 + arow) * K + scol;
  const bf16* gB0 = Bm + (size_t)(bn + arow) * K + scol;
  const bf16* gB1 = Bm + (size_t)(bn + 128 + arow) * K + scol;
  char* lA0 = (char*)As + arow * 64 + slot * 16;
  char* lB0 = (char*)Bs + arow * 64 + slot * 16;

#define STAGE256(kt) do {                                   \
    const int bi_ = (kt) & 3;                               \
    const size_t ko_ = (size_t)(kt) << 5;                   \
    gload_lds16(gA0 + ko_, lA0 + bi_ * 16384);              \
    gload_lds16(gA1 + ko_, lA0 + 8192 + bi_ * 16384);       \
    gload_lds16(gB0 + ko_, lB0 + bi_ * 16384);              \
    gload_lds16(gB1 + ko_, lB0 + 8192 + bi_ * 16384);       \
  } while (0)

  const int aoff = ((fq ^ (fr & 3) ^ ((fr >> 2) & 3)) << 4);
  const char* rA = (char*)As + aoff + (wm * 128 + fr) * 64;
  const char* rB = (char*)Bs + aoff + (wn * 64 + fr) * 64;

  floatx4 acc[8][4];
  #pragma unroll
  for (int m = 0; m < 8; ++m)
    #pragma unroll
    for (int n = 0; n < 4; ++n)
      #pragma unroll
      for (int r = 0; r < 4; ++r) acc[m][n][r] = 0.f;

  STAGE256(0);
  STAGE256(1);
  STAGE256(2);
  __builtin_amdgcn_sched_barrier(0);
  asm volatile("s_waitcnt vmcnt(8)" ::: "memory");
  __builtin_amdgcn_s_barrier();
  __builtin_amdgcn_sched_barrier(0);

  for (int kt = 0; kt < NT; ++kt) {
    const int bi = kt & 3;
    if (kt + 3 < NT) STAGE256(kt + 3);
    const char* pa = rA + bi * 16384;
    const char* pb = rB + bi * 16384;
    bf16x8 a8[8], b8[4];
    #pragma unroll
    for (int m = 0; m < 8; ++m) a8[m] = *(const bf16x8*)(pa + m * 1024);
    #pragma unroll
    for (int n = 0; n < 4; ++n) b8[n] = *(const bf16x8*)(pb + n * 1024);
    __builtin_amdgcn_s_setprio(1);
    #pragma unroll
    for (int m = 0; m < 8; ++m)
      #pragma unroll
      for (int n = 0; n < 4; ++n)
        acc[m][n] = __builtin_amdgcn_mfma_f32_16x16x32_bf16(a8[m], b8[n], acc[m][n], 0, 0, 0);
    __builtin_amdgcn_s_setprio(0);
    if (kt < NT - 1) {
      __builtin_amdgcn_sched_barrier(0);
      if (kt <= NT - 4)      { asm volatile("s_waitcnt vmcnt(8)" ::: "memory"); }
      else if (kt == NT - 3) { asm volatile("s_waitcnt vmcnt(4)" ::: "memory"); }
      else                   { asm volatile("s_waitcnt vmcnt(0)" ::: "memory"); }
      __builtin_amdgcn_s_barrier();
      __builtin_amdgcn_sched_barrier(0);
    }
  }
#undef STAGE256

  #pragma unroll
  for (int m = 0; m < 8; ++m) {
    const int row = bm + wm * 128 + (m << 4) + (fq << 2);
    #pragma unroll
    for (int n = 0; n < 4; ++n) {
      const int col = bn + wn * 64 + (n << 4) + fr;
      #pragma unroll
      for (int r = 0; r < 4; ++r)
        C[(size_t)(row + r) * N + col] = (bf16)acc[m][n][r];
    }
  }
}

// ---------------- split-K GEMM: block z computes K-slice, PT partials ----------------
template <typename PT>
__global__ __launch_bounds__(256) void gemm_bt_sk(const bf16* __restrict__ A,
                                                  const bf16* __restrict__ Bm,
                                                  PT* __restrict__ Cp,
                                                  int M, int N, int ldk, int KS) {
  __shared__ bf16 As[128 * 32];
  __shared__ bf16 Bs[128 * 32];
  const int tid  = threadIdx.x;
  const int lane = tid & 63;
  const int wave = tid >> 6;
  const int bm = blockIdx.y * 128;
  const int bn = blockIdx.x * 128;
  const int z  = blockIdx.z;
  const int wr = (wave >> 1) << 6;
  const int wc = (wave & 1) << 6;
  const int fr = lane & 15;
  const int fq = lane >> 4;

  const int srow  = tid >> 2;
  const int skoff = (tid & 3) << 3;
  const size_t kbase = (size_t)z * KS + skoff;
  const bf16* ga0 = A  + (size_t)(bm + srow) * ldk + kbase;
  const bf16* ga1 = A  + (size_t)(bm + 64 + srow) * ldk + kbase;
  const bf16* gb0 = Bm + (size_t)(bn + srow) * ldk + kbase;
  const bf16* gb1 = Bm + (size_t)(bn + 64 + srow) * ldk + kbase;
  char* la0 = (char*)As + (wave << 10);
  char* la1 = (char*)As + 4096 + (wave << 10);
  char* lb0 = (char*)Bs + (wave << 10);
  char* lb1 = (char*)Bs + 4096 + (wave << 10);

  floatx4 acc[4][4];
  #pragma unroll
  for (int i = 0; i < 4; ++i)
    #pragma unroll
    for (int j = 0; j < 4; ++j)
      #pragma unroll
      for (int r = 0; r < 4; ++r) acc[i][j][r] = 0.f;

  for (int k0 = 0; k0 < KS; k0 += 32) {
    gload_lds16(ga0 + k0, la0);
    gload_lds16(ga1 + k0, la1);
    gload_lds16(gb0 + k0, lb0);
    gload_lds16(gb1 + k0, lb1);
    __syncthreads();
    bf16x8 af[4], bfr[4];
    #pragma unroll
    for (int i = 0; i < 4; ++i)
      af[i] = *(const bf16x8*)&As[(wr + (i << 4) + fr) * 32 + (fq << 3)];
    #pragma unroll
    for (int j = 0; j < 4; ++j)
      bfr[j] = *(const bf16x8*)&Bs[(wc + (j << 4) + fr) * 32 + (fq << 3)];
    #pragma unroll
    for (int i = 0; i < 4; ++i)
      #pragma unroll
      for (int j = 0; j < 4; ++j)
        acc[i][j] = __builtin_amdgcn_mfma_f32_16x16x32_bf16(af[i], bfr[j], acc[i][j], 0, 0, 0);
    __syncthreads();
  }
  PT* Cb = Cp + (size_t)z * M * N;
  #pragma unroll
  for (int i = 0; i < 4; ++i) {
    const int row = bm + wr + (i << 4) + (fq << 2);
    #pragma unroll
    for (int j = 0; j < 4; ++j) {
      const int col = bn + wc + (j << 4) + fr;
      #pragma unroll
      for (int r = 0; r < 4; ++r)
        Cb[(size_t)(row + r) * N + col] = (PT)acc[i][j][r];
    }
  }
}

// fixed-order split-K reduce -> f32 (deterministic)
template <int KS, typename PT>
__global__ __launch_bounds__(256) void reduce_sk_k(const PT* __restrict__ part,
                                                   float* __restrict__ out,
                                                   int n4, size_t mn) {
  const int i = blockIdx.x * 256 + threadIdx.x;
  if (i >= n4) return;
  const size_t e = (size_t)i * 4;
  floatx4 s = {0.f, 0.f, 0.f, 0.f};
  #pragma unroll
  for (int z = 0; z < KS; ++z) {
    const PT* p = &part[(size_t)z * mn + e];
    #pragma unroll
    for (int j = 0; j < 4; ++j) s[j] += (float)p[j];
  }
  *(floatx4*)&out[e] = s;
}

// ---------------- depthwise causal conv(4) + bias + SiLU ----------------
__global__ __launch_bounds__(256) void conv_silu_k(const bf16* __restrict__ xr,
                                                   const float* __restrict__ cw,
                                                   const float* __restrict__ cb,
                                                   bf16* __restrict__ u_btd,
                                                   bf16* __restrict__ u_dtl) {
  __shared__ float tile[32][65];
  const int tid = threadIdx.x;
  const int d0 = blockIdx.x << 6;
  const int t0 = blockIdx.y << 5;
  const int b  = blockIdx.z;
  const int dl = tid & 63, tq = tid >> 6;
  const int d  = d0 + dl;
  const float w0 = cw[d * 4 + 0], w1 = cw[d * 4 + 1], w2 = cw[d * 4 + 2], w3 = cw[d * 4 + 3];
  const float bias = cb[d];
  #pragma unroll
  for (int i = 0; i < 8; ++i) {
    const int t = tq * 8 + i;
    const int tg = t0 + t;
    float acc = bias;
    {
      int tt = tg - 3;
      if (tt >= 0) acc += w0 * (float)xr[((size_t)b * SEQLEN + tt) * 4096 + d];
    }
    {
      int tt = tg - 2;
      if (tt >= 0) acc += w1 * (float)xr[((size_t)b * SEQLEN + tt) * 4096 + d];
    }
    {
      int tt = tg - 1;
      if (tt >= 0) acc += w2 * (float)xr[((size_t)b * SEQLEN + tt) * 4096 + d];
    }
    acc += w3 * (float)xr[((size_t)b * SEQLEN + tg) * 4096 + d];
    const float uval = siluf_(acc);
    u_btd[((size_t)b * SEQLEN + tg) * DINNER + d] = (bf16)uval;
    tile[t][dl] = uval;
  }
  __syncthreads();
  const int dr = tid >> 2;
  const int tcol = (tid & 3) << 3;
  bf16x8 ov;
  #pragma unroll
  for (int i = 0; i < 8; ++i) ov[i] = (bf16)tile[tcol + i][dr];
  *(bf16x8*)&u_dtl[((size_t)b * DINNER + d0 + dr) * SEQLEN + t0 + tcol] = ov;
}

// ---------------- dt projection + softplus + clamp -> bf16 (b,d,t) ----------------
__global__ __launch_bounds__(256) void dtproj_k(const float* __restrict__ x_dbl,
                                                const float* __restrict__ w,
                                                const float* __restrict__ bias,
                                                bf16* __restrict__ dt_t) {
  __shared__ float r_s[64][65];
  __shared__ float w_s[64][65];
  const int tid  = threadIdx.x;
  const int d0   = blockIdx.x << 6;
  const int row0 = blockIdx.y << 6;
  #pragma unroll
  for (int j = 0; j < 4; ++j) {
    int id = tid + (j << 8);
    int r  = id >> 4;
    int kq = (id & 15) << 2;
    floatx4 v = *(const floatx4*)&x_dbl[(size_t)(row0 + r) * NPROJ + kq];
    r_s[r][kq] = v[0]; r_s[r][kq + 1] = v[1]; r_s[r][kq + 2] = v[2]; r_s[r][kq + 3] = v[3];
    floatx4 ww = *(const floatx4*)&w[(size_t)(d0 + r) * 64 + kq];
    w_s[r][kq] = ww[0]; w_s[r][kq + 1] = ww[1]; w_s[r][kq + 2] = ww[2]; w_s[r][kq + 3] = ww[3];
  }
  __syncthreads();
  const int tl = tid & 15, dl = tid >> 4;
  float acc[4][4] = {};
  #pragma unroll 8
  for (int k = 0; k < 64; ++k) {
    float a[4], bb[4];
    #pragma unroll
    for (int i = 0; i < 4; ++i) a[i] = r_s[tl * 4 + i][k];
    #pragma unroll
    for (int j = 0; j < 4; ++j) bb[j] = w_s[dl + (j << 4)][k];
    #pragma unroll
    for (int i = 0; i < 4; ++i)
      #pragma unroll
      for (int j = 0; j < 4; ++j) acc[i][j] += a[i] * bb[j];
  }
  const int bb_ = row0 >> 11;
  const int tbase = (row0 & 2047) + tl * 4;
  #pragma unroll
  for (int j = 0; j < 4; ++j) {
    const int dd = d0 + dl + (j << 4);
    const float bsv = bias[dd];
    bf16x4 o;
    #pragma unroll
    for (int i = 0; i < 4; ++i) {
      float v = acc[i][j] + bsv;
      float sp = (v > 20.f) ? v : __logf(1.f + __expf(v));
      o[i] = (bf16)fminf(sp, 10.f);
    }
    *(bf16x4*)&dt_t[((size_t)bb_ * DINNER + dd) * SEQLEN + tbase] = o;
  }
}

// ---------------- chunked selective scan, s-split-2: thread owns (b,d,chunk,s-half) ----------------
// wave layout: lanes 0-31 = s-half 0, lanes 32-63 = s-half 1, same 32 d's. shfl_xor(32) combines.
__global__ __launch_bounds__(256) void scanA_k(const bf16* __restrict__ dt_t,
                                               const bf16* __restrict__ u_dtl,
                                               const float* __restrict__ x_dbl,
                                               const float* __restrict__ A_log,
                                               float* __restrict__ hfin,
                                               float* __restrict__ Pbuf) {
  __shared__ float Bs_[TCC][16];
  const int tid = threadIdx.x;
  const int b = blockIdx.z, c = blockIdx.y;
  const int wave = tid >> 6, lane = tid & 63;
  const int sh = lane >> 5;
  const int dl = (wave << 5) + (lane & 31);
  const int d  = (blockIdx.x << 7) + dl;
  const int t0 = c * TCC;
  if (tid < TCC * 4) {
    const int t = tid >> 2, sq = (tid & 3) << 2;
    *(floatx4*)&Bs_[t][sq] = *(const floatx4*)&x_dbl[((size_t)b * SEQLEN + t0 + t) * NPROJ + 64 + sq];
  }
  const int s0 = sh << 3;
  float Ae[8];
  {
    floatx4 a0 = *(const floatx4*)&A_log[d * DSTATE + s0];
    floatx4 a1 = *(const floatx4*)&A_log[d * DSTATE + s0 + 4];
    #pragma unroll
    for (int j = 0; j < 4; ++j) { Ae[j] = -__expf(a0[j]) * LOG2E; Ae[4 + j] = -__expf(a1[j]) * LOG2E; }
  }
  __syncthreads();
  float h[8];
  #pragma unroll
  for (int s = 0; s < 8; ++s) h[s] = 0.f;
  float sdt = 0.f;
  const bf16* dtp = dt_t + ((size_t)b * DINNER + d) * SEQLEN + t0;
  const bf16* up  = u_dtl + ((size_t)b * DINNER + d) * SEQLEN + t0;
  for (int tq = 0; tq < TCC; tq += 8) {
    bf16x8 dt8 = *(const bf16x8*)&dtp[tq];
    bf16x8 u8  = *(const bf16x8*)&up[tq];
    #pragma unroll
    for (int j = 0; j < 8; ++j) {
      const float dtv = (float)dt8[j];
      const float xin = dtv * (float)u8[j];
      sdt += dtv;
      const floatx4 B0 = *(const floatx4*)&Bs_[tq + j][s0];
      const floatx4 B1 = *(const floatx4*)&Bs_[tq + j][s0 + 4];
      #pragma unroll
      for (int s = 0; s < 4; ++s) {
        h[s]     = EXP2F(dtv * Ae[s]) * h[s]     + xin * B0[s];
        h[4 + s] = EXP2F(dtv * Ae[4 + s]) * h[4 + s] + xin * B1[s];
      }
    }
  }
  const size_t base = (((size_t)b * NCHUNK + c) * DINNER + d) * DSTATE + s0;
  floatx4 hv0, hv1, pv0, pv1;
  #pragma unroll
  for (int j = 0; j < 4; ++j) {
    hv0[j] = h[j];     pv0[j] = EXP2F(Ae[j] * sdt);
    hv1[j] = h[4 + j]; pv1[j] = EXP2F(Ae[4 + j] * sdt);
  }
  *(floatx4*)&hfin[base] = hv0;     *(floatx4*)&hfin[base + 4] = hv1;
  *(floatx4*)&Pbuf[base] = pv0;     *(floatx4*)&Pbuf[base + 4] = pv1;
}

__global__ __launch_bounds__(256) void scanB_k(const float* __restrict__ hfin,
                                               const float* __restrict__ Pbuf,
                                               float* __restrict__ hin) {
  const int flat = blockIdx.x * 256 + threadIdx.x;
  const int b  = flat >> 15;
  const int ds = flat & 32767;
  float h = 0.f;
  hin[((size_t)b * NCHUNK) * 32768 + ds] = 0.f;
  for (int c = 1; c < NCHUNK; ++c) {
    const size_t prev = ((size_t)(b * NCHUNK + c - 1)) * 32768 + ds;
    h = hfin[prev] + Pbuf[prev] * h;
    hin[((size_t)(b * NCHUNK + c)) * 32768 + ds] = h;
  }
}

__global__ __launch_bounds__(256) void scanC_k(const bf16* __restrict__ dt_t,
                                               const bf16* __restrict__ u_dtl,
                                               const float* __restrict__ x_dbl,
                                               const float* __restrict__ A_log,
                                               const float* __restrict__ Dp,
                                               const float* __restrict__ hin,
                                               const bf16* __restrict__ xr,
                                               bf16* __restrict__ yres) {
  __shared__ float Bs_[TCC][16];
  __shared__ float Cs_[TCC][16];
  const int tid = threadIdx.x;
  const int b = blockIdx.z, c = blockIdx.y;
  const int wave = tid >> 6, lane = tid & 63;
  const int sh = lane >> 5;
  const int dl = (wave << 5) + (lane & 31);
  const int d  = (blockIdx.x << 7) + dl;
  const int t0 = c * TCC;
  if (tid < TCC * 4) {
    const int t = tid >> 2, sq = (tid & 3) << 2;
    *(floatx4*)&Bs_[t][sq] = *(const floatx4*)&x_dbl[((size_t)b * SEQLEN + t0 + t) * NPROJ + 64 + sq];
    *(floatx4*)&Cs_[t][sq] = *(const floatx4*)&x_dbl[((size_t)b * SEQLEN + t0 + t) * NPROJ + 80 + sq];
  }
  const int s0 = sh << 3;
  float Ae[8];
  {
    floatx4 a0 = *(const floatx4*)&A_log[d * DSTATE + s0];
    floatx4 a1 = *(const floatx4*)&A_log[d * DSTATE + s0 + 4];
    #pragma unroll
    for (int j = 0; j < 4; ++j) { Ae[j] = -__expf(a0[j]) * LOG2E; Ae[4 + j] = -__expf(a1[j]) * LOG2E; }
  }
  float h[8];
  const size_t base = (((size_t)b * NCHUNK + c) * DINNER + d) * DSTATE + s0;
  {
    floatx4 h0 = *(const floatx4*)&hin[base];
    floatx4 h1 = *(const floatx4*)&hin[base + 4];
    #pragma unroll
    for (int j = 0; j < 4; ++j) { h[j] = h0[j]; h[4 + j] = h1[j]; }
  }
  const float Dv = Dp[d];
  __syncthreads();
  const bf16* dtp = dt_t + ((size_t)b * DINNER + d) * SEQLEN + t0;
  const bf16* up  = u_dtl + ((size_t)b * DINNER + d) * SEQLEN + t0;
  const bf16* resp = xr + ((size_t)b * SEQLEN + t0) * 4096 + 2048 + d;
  bf16* yp = yres + ((size_t)b * SEQLEN + t0) * DINNER + d;
  for (int tq = 0; tq < TCC; tq += 8) {
    bf16x8 dt8 = *(const bf16x8*)&dtp[tq];
    bf16x8 u8  = *(const bf16x8*)&up[tq];
    #pragma unroll
    for (int j = 0; j < 8; ++j) {
      const int t = tq + j;
      const float dtv = (float)dt8[j];
      const float uv  = (float)u8[j];
      const float xin = dtv * uv;
      const floatx4 B0 = *(const floatx4*)&Bs_[t][s0];
      const floatx4 B1 = *(const floatx4*)&Bs_[t][s0 + 4];
      const floatx4 C0 = *(const floatx4*)&Cs_[t][s0];
      const floatx4 C1 = *(const floatx4*)&Cs_[t][s0 + 4];
      float a0 = 0.f, a1 = 0.f;
      #pragma unroll
      for (int s = 0; s < 4; ++s) {
        h[s]     = EXP2F(dtv * Ae[s]) * h[s]     + xin * B0[s];
        h[4 + s] = EXP2F(dtv * Ae[4 + s]) * h[4 + s] + xin * B1[s];
        a0 += h[s] * C0[s];
        a1 += h[4 + s] * C1[s];
      }
      float acc = a0 + a1;
      acc += __shfl_xor(acc, 32);
      if (sh == 0) {
        const float r = (float)resp[(size_t)t * 4096];
        yp[(size_t)t * DINNER] = (bf16)((acc + Dv * uv) * siluf_(r));
      }
    }
  }
}

extern "C" void kernel_launch(void* const* d_in, const int* in_sizes, int n_in,
                              void* d_out, int out_size, void* d_ws, size_t ws_size,
                              hipStream_t stream) {
  const float* x         = (const float*)d_in[0];
  const float* in_proj_w = (const float*)d_in[1];
  const float* conv_w    = (const float*)d_in[2];
  const float* conv_b    = (const float*)d_in[3];
  const float* x_proj_w  = (const float*)d_in[4];
  const float* dt_proj_w = (const float*)d_in[5];
  const float* dt_proj_b = (const float*)d_in[6];
  const float* A_log     = (const float*)d_in[7];
  const float* Dp        = (const float*)d_in[8];
  const float* out_proj_w= (const float*)d_in[9];
  float* out = (float*)d_out;

  char* ws = (char*)d_ws;
  size_t off = 0;
  auto alloc = [&](size_t bytes) -> void* {
    void* p = ws + off;
    off += (bytes + 255) & ~(size_t)255;
    return p;
  };
  // long-lived buffers first
  bf16*  wo_bf  = (bf16*) alloc((size_t)DMODEL * DINNER * 2);
  bf16*  xw_bf  = (bf16*) alloc((size_t)NPROJ * DINNER * 2);
  bf16*  yres   = (bf16*) alloc((size_t)NROWS * DINNER * 2);
  float* x_dbl  = (float*)alloc((size_t)NROWS * NPROJ * 4);
  bf16*  dt_t   = (bf16*) alloc((size_t)BATCH * DINNER * SEQLEN * 2);
  bf16*  u_dtl  = (bf16*) alloc((size_t)BATCH * DINNER * SEQLEN * 2);
  float* hfin   = (float*)alloc((size_t)BATCH * NCHUNK * DINNER * DSTATE * 4);
  float* Pbuf   = (float*)alloc((size_t)BATCH * NCHUNK * DINNER * DSTATE * 4);
  float* hin    = (float*)alloc((size_t)BATCH * NCHUNK * DINNER * DSTATE * 4);
  // overlay region: early-dead buffers, later reused for split-K partials
  const size_t mark = off;
  bf16*  x_bf   = (bf16*) alloc((size_t)NROWS * DMODEL * 2);      // dead after in_proj
  bf16*  wi_bf  = (bf16*) alloc((size_t)2 * DINNER * DMODEL * 2); // dead after in_proj
  bf16*  xr     = (bf16*) alloc((size_t)NROWS * 4096 * 2);        // dead after scanC
  bf16*  u_btd  = (bf16*) alloc((size_t)NROWS * DINNER * 2);      // dead after x_proj
  float* xpart  = (float*)(ws + mark);   // f32 x8, aliases x_bf+wi_bf (dead by x_proj)
  bf16*  opart  = (bf16*)(ws + mark);    // bf16 x4, aliases all 4 (dead by out_proj)

  cast_all_k<<<CAST_TOT4 / 256, 256, 0, stream>>>(x, in_proj_w, out_proj_w, x_proj_w,
                                                  x_bf, wi_bf, wo_bf, xw_bf);
  // in_proj
  gemm_bt_256<<<dim3(4096 / 256, NROWS / 256), 512, 0, stream>>>(x_bf, wi_bf, xr, NROWS, 4096, DMODEL);
  // conv + SiLU
  conv_silu_k<<<dim3(DINNER / 64, SEQLEN / 32, BATCH), 256, 0, stream>>>(xr, conv_w, conv_b, u_btd, u_dtl);
  // x_proj split-K x8 (f32 partials)
  gemm_bt_sk<float><<<dim3(1, 32, 8), 256, 0, stream>>>(u_btd, xw_bf, xpart, NROWS, NPROJ, DINNER, DINNER / 8);
  reduce_sk_k<8, float><<<(NROWS * NPROJ / 4 + 255) / 256, 256, 0, stream>>>(xpart, x_dbl, NROWS * NPROJ / 4, (size_t)NROWS * NPROJ);
  // dt proj
  dtproj_k<<<dim3(DINNER / 64, NROWS / 64), 256, 0, stream>>>(x_dbl, dt_proj_w, dt_proj_b, dt_t);
  // chunked selective scan (s-split-2)
  scanA_k<<<dim3(DINNER / 128, NCHUNK, BATCH), 256, 0, stream>>>(dt_t, u_dtl, x_dbl, A_log, hfin, Pbuf);
  scanB_k<<<dim3(BATCH * DINNER * DSTATE / 256), 256, 0, stream>>>(hfin, Pbuf, hin);
  scanC_k<<<dim3(DINNER / 128, NCHUNK, BATCH), 256, 0, stream>>>(dt_t, u_dtl, x_dbl, A_log, Dp, hin, xr, yres);
  // out_proj split-K x4 (bf16 partials)
  gemm_bt_sk<bf16><<<dim3(DMODEL / 128, NROWS / 128, 4), 256, 0, stream>>>(yres, wo_bf, opart, NROWS, DMODEL, DINNER, DINNER / 4);
  reduce_sk_k<4, bf16><<<(NROWS * DMODEL / 4 + 255) / 256, 256, 0, stream>>>(opart, out, NROWS * DMODEL / 4, (size_t)NROWS * DMODEL);
}